// Round 1
// baseline (875.486 us; speedup 1.0000x reference)
//
#include <hip/hip_runtime.h>

#define N0 4096
#define P1K 2048
#define P2K 1024

// ---------------- helpers ----------------
__device__ __forceinline__ float blockReduceSum256(float v) {
  __shared__ float sh[16];
  int lane = threadIdx.x & 63;
  int w = threadIdx.x >> 6;
#pragma unroll
  for (int o = 32; o > 0; o >>= 1) v += __shfl_down(v, o, 64);
  __syncthreads();
  if (lane == 0) sh[w] = v;
  __syncthreads();
  float r = 0.f;
  if (threadIdx.x == 0) {
    int nw = (blockDim.x + 63) >> 6;
    for (int i = 0; i < nw; ++i) r += sh[i];
  }
  return r;  // valid on thread 0 only
}

// ---------------- graph build ----------------
__global__ void count_edges(const int* __restrict__ src, const int* __restrict__ dst,
                            int* __restrict__ co, int* __restrict__ ci, int E) {
  int e = blockIdx.x * blockDim.x + threadIdx.x;
  if (e >= E) return;
  atomicAdd(&co[src[e]], 1);
  atomicAdd(&ci[dst[e]], 1);
}

__global__ __launch_bounds__(1024) void exscan4096(const int* __restrict__ cnt,
                                                   int* __restrict__ ptr) {
  __shared__ int ls[1024];
  int t = threadIdx.x;
  int v0 = cnt[t * 4], v1 = cnt[t * 4 + 1], v2 = cnt[t * 4 + 2], v3 = cnt[t * 4 + 3];
  int s = v0 + v1 + v2 + v3;
  ls[t] = s;
  __syncthreads();
  for (int off = 1; off < 1024; off <<= 1) {
    int x = (t >= off) ? ls[t - off] : 0;
    __syncthreads();
    ls[t] += x;
    __syncthreads();
  }
  int ex = (t > 0) ? ls[t - 1] : 0;
  ptr[t * 4]     = ex;
  ptr[t * 4 + 1] = ex + v0;
  ptr[t * 4 + 2] = ex + v0 + v1;
  ptr[t * 4 + 3] = ex + v0 + v1 + v2;
  if (t == 1023) ptr[4096] = ex + s;
}

__global__ void fill_edges(const int* __restrict__ src, const int* __restrict__ dst,
                           const int* __restrict__ optr, const int* __restrict__ iptr,
                           int* __restrict__ fo, int* __restrict__ fi,
                           int* __restrict__ odst, int* __restrict__ isrc, int E) {
  int e = blockIdx.x * blockDim.x + threadIdx.x;
  if (e >= E) return;
  int s = src[e], d = dst[e];
  odst[optr[s] + atomicAdd(&fo[s], 1)] = d;
  isrc[iptr[d] + atomicAdd(&fi[d], 1)] = s;
}

__global__ void dinv0_kernel(const int* __restrict__ optr, float* __restrict__ dinv0) {
  int i = blockIdx.x * blockDim.x + threadIdx.x;
  if (i < N0) dinv0[i] = rsqrtf((float)(optr[i + 1] - optr[i]) + 1.0f);
}

// ---------------- dense matmul: C[M,N] = A@B (TA=0) or A^T@B (TA=1, A is [K,M]) ----
template <bool TRANS_A>
__global__ void mm_kernel(const float* __restrict__ A, const float* __restrict__ B,
                          float* __restrict__ C, int M, int N, int K) {
  __shared__ float As[16][64];
  __shared__ float Bs[16][64];
  int tid = threadIdx.x;
  int nbx = N >> 6;
  int by = blockIdx.x / nbx, bx = blockIdx.x % nbx;
  int row0 = by << 6, col0 = bx << 6;
  int tx = tid & 15, ty = tid >> 4;
  float acc[4][4] = {{0.f}};
  for (int k0 = 0; k0 < K; k0 += 16) {
    if (TRANS_A) {
#pragma unroll
      for (int p = 0; p < 4; ++p) {
        int kk = (tid >> 6) + (p << 2);
        int i = tid & 63;
        As[kk][i] = A[(size_t)(k0 + kk) * M + row0 + i];
      }
    } else {
#pragma unroll
      for (int p = 0; p < 4; ++p) {
        int r = (tid >> 4) + (p << 4);
        int kk = tid & 15;
        As[kk][r] = A[(size_t)(row0 + r) * K + k0 + kk];
      }
    }
#pragma unroll
    for (int p = 0; p < 4; ++p) {
      int kk = (tid >> 6) + (p << 2);
      int c = tid & 63;
      Bs[kk][c] = B[(size_t)(k0 + kk) * N + col0 + c];
    }
    __syncthreads();
#pragma unroll
    for (int kk = 0; kk < 16; ++kk) {
      float a[4], b[4];
#pragma unroll
      for (int i = 0; i < 4; ++i) a[i] = As[kk][(ty << 2) + i];
#pragma unroll
      for (int j = 0; j < 4; ++j) b[j] = Bs[kk][(tx << 2) + j];
#pragma unroll
      for (int i = 0; i < 4; ++i)
#pragma unroll
        for (int j = 0; j < 4; ++j) acc[i][j] += a[i] * b[j];
    }
    __syncthreads();
  }
#pragma unroll
  for (int i = 0; i < 4; ++i) {
    int r = row0 + (ty << 2) + i;
#pragma unroll
    for (int j = 0; j < 4; ++j) C[(size_t)r * N + col0 + (tx << 2) + j] = acc[i][j];
  }
}

// W2[a,b] = sum_k A1[p2[a],k] * A1[k,p2[b]],  A1 = W1 + I  (inline gathers)
__global__ void mm_w2(const float* __restrict__ W1, const int* __restrict__ perm2,
                      float* __restrict__ W2) {
  __shared__ float As[16][64];
  __shared__ float Bs[16][64];
  int tid = threadIdx.x;
  int by = blockIdx.x >> 4, bx = blockIdx.x & 15;
  int row0 = by << 6, col0 = bx << 6;
  int tx = tid & 15, ty = tid >> 4;
  float acc[4][4] = {{0.f}};
  for (int k0 = 0; k0 < 2048; k0 += 16) {
#pragma unroll
    for (int p = 0; p < 4; ++p) {
      int r = (tid >> 4) + (p << 4);
      int kk = tid & 15;
      int pr = perm2[row0 + r];
      int kc = k0 + kk;
      As[kk][r] = W1[(size_t)pr * 2048 + kc] + ((kc == pr) ? 1.f : 0.f);
    }
#pragma unroll
    for (int p = 0; p < 4; ++p) {
      int kk = (tid >> 6) + (p << 2);
      int c = tid & 63;
      int pc = perm2[col0 + c];
      int kr = k0 + kk;
      Bs[kk][c] = W1[(size_t)kr * 2048 + pc] + ((kr == pc) ? 1.f : 0.f);
    }
    __syncthreads();
#pragma unroll
    for (int kk = 0; kk < 16; ++kk) {
      float a[4], b[4];
#pragma unroll
      for (int i = 0; i < 4; ++i) a[i] = As[kk][(ty << 2) + i];
#pragma unroll
      for (int j = 0; j < 4; ++j) b[j] = Bs[kk][(tx << 2) + j];
#pragma unroll
      for (int i = 0; i < 4; ++i)
#pragma unroll
        for (int j = 0; j < 4; ++j) acc[i][j] += a[i] * b[j];
    }
    __syncthreads();
  }
#pragma unroll
  for (int i = 0; i < 4; ++i) {
    int r = row0 + (ty << 2) + i;
#pragma unroll
    for (int j = 0; j < 4; ++j) W2[(size_t)r * 1024 + col0 + (tx << 2) + j] = acc[i][j];
  }
}

// ---------------- elementwise / epilogues ----------------
__global__ void scale_rows(float* __restrict__ Z, const float* __restrict__ dinv,
                           int C, int total) {
  int idx = blockIdx.x * blockDim.x + threadIdx.x;
  if (idx >= total) return;
  Z[idx] *= dinv[idx / C];
}

__global__ void gcn_epi(const float* __restrict__ Y, const float* __restrict__ Z,
                        const float* __restrict__ dinv, const float* __restrict__ bias,
                        float* __restrict__ outp, int C, int total) {
  int idx = blockIdx.x * blockDim.x + threadIdx.x;
  if (idx >= total) return;
  int i = idx / C, c = idx % C;
  outp[idx] = fmaxf(dinv[i] * (Y[idx] + Z[idx]) + bias[c], 0.f);
}

__global__ void gather_scale(const float* __restrict__ X, const int* __restrict__ perm,
                             const float* __restrict__ vals, float* __restrict__ outp,
                             int C, int total) {
  int idx = blockIdx.x * blockDim.x + threadIdx.x;
  if (idx >= total) return;
  int a = idx / C, c = idx % C;
  outp[idx] = X[(size_t)perm[a] * C + c] * vals[a];
}

// out = base + scatter(up) via rank (in-place safe: out may alias base)
__global__ void add_up(const float* base, const int* __restrict__ rank,
                       const float* __restrict__ up, float* outp, int C, int total) {
  int idx = blockIdx.x * blockDim.x + threadIdx.x;
  if (idx >= total) return;
  int r = idx / C, c = idx % C;
  int rk = rank[r];
  float v = base[idx];
  if (rk >= 0) v += up[(size_t)rk * C + c];
  outp[idx] = v;
}

__global__ void score_kernel(const float* __restrict__ X, int C,
                             const float* __restrict__ p, float* __restrict__ sc) {
  int i = blockIdx.x;
  float s1 = 0.f, s2 = 0.f;
  for (int c = threadIdx.x; c < C; c += blockDim.x) {
    float pv = p[c];
    s1 += pv * pv;
    s2 += X[(size_t)i * C + c] * pv;
  }
  float r1 = blockReduceSum256(s1);
  __syncthreads();
  float r2 = blockReduceSum256(s2);
  if (threadIdx.x == 0) sc[i] = tanhf(r2 / sqrtf(r1));
}

__global__ __launch_bounds__(1024) void topk_kernel(const float* __restrict__ score, int n,
                                                    int k, int* __restrict__ perm,
                                                    float* __restrict__ vals,
                                                    int* __restrict__ rank) {
  __shared__ float s[4096];
  __shared__ int id[4096];
  for (int i = threadIdx.x; i < n; i += blockDim.x) { s[i] = score[i]; id[i] = i; }
  __syncthreads();
  for (int size = 2; size <= n; size <<= 1) {
    for (int stride = size >> 1; stride > 0; stride >>= 1) {
      for (int i = threadIdx.x; i < n; i += blockDim.x) {
        int j = i ^ stride;
        if (j > i) {
          float si = s[i], sj = s[j];
          int ii = id[i], ij = id[j];
          bool iFirst = (si > sj) || (si == sj && ii < ij);  // desc score, asc idx
          bool up = ((i & size) == 0);
          if (up ? !iFirst : iFirst) { s[i] = sj; s[j] = si; id[i] = ij; id[j] = ii; }
        }
      }
      __syncthreads();
    }
  }
  for (int t = threadIdx.x; t < n; t += blockDim.x) {
    int node = id[t];
    rank[node] = (t < k) ? t : -1;
    if (t < k) { perm[t] = node; vals[t] = s[t]; }
  }
}

// W1[a,b] = sum_k A[pa,k]*A[k,pb] (A = W+I, sparse enumeration), diag zeroed; dinv1 out
__global__ void build_W1(const int* __restrict__ optr, const int* __restrict__ odst,
                         const int* __restrict__ perm1, const int* __restrict__ rank1,
                         float* __restrict__ W1, float* __restrict__ dinv1) {
  __shared__ float row[2048];
  int a = blockIdx.x;
  int pa = perm1[a];
  for (int i = threadIdx.x; i < 2048; i += blockDim.x) row[i] = 0.f;
  __syncthreads();
  int kbeg = optr[pa], kend = optr[pa + 1];
  for (int kk = kbeg - 1; kk < kend; ++kk) {  // kk==kbeg-1 -> k=pa (the +I term)
    int k = (kk < kbeg) ? pa : odst[kk];
    int jbeg = optr[k], jend = optr[k + 1];
    for (int jj = jbeg - 1 + (int)threadIdx.x; jj < jend; jj += (int)blockDim.x) {
      int j = (jj < jbeg) ? k : odst[jj];  // jj==jbeg-1 -> j=k (the +I term)
      int rb = rank1[j];
      if (rb >= 0) atomicAdd(&row[rb], 1.0f);
    }
  }
  __syncthreads();
  float ssum = 0.f;
  for (int i = threadIdx.x; i < 2048; i += blockDim.x) {
    float v = (i == a) ? 0.f : row[i];  // remove_self_loops
    W1[(size_t)a * 2048 + i] = v;
    ssum += v;
  }
  float t = blockReduceSum256(ssum);
  if (threadIdx.x == 0) dinv1[a] = rsqrtf(t + 1.0f);
}

__global__ void postW2(float* __restrict__ W2, float* __restrict__ dinv2) {
  int a = blockIdx.x;
  float ssum = 0.f;
  for (int i = threadIdx.x; i < 1024; i += blockDim.x) {
    float v = W2[(size_t)a * 1024 + i];
    if (i == a) { W2[(size_t)a * 1024 + i] = 0.f; v = 0.f; }
    ssum += v;
  }
  float t = blockReduceSum256(ssum);
  if (threadIdx.x == 0) dinv2[a] = rsqrtf(t + 1.0f);
}

__global__ void mean_cols(const float* __restrict__ X, int R, int C, float* __restrict__ outp) {
  int c = blockIdx.x;
  float s = 0.f;
  for (int r = threadIdx.x; r < R; r += blockDim.x) s += X[(size_t)r * C + c];
  float t = blockReduceSum256(s);
  if (threadIdx.x == 0) outp[c] = t / (float)R;
}

// level-0 SpMM epilogue: out[i,c] = relu(dinv[i]*(sum_{r in in(i)} Z[r,c] + Z[i,c]) + b[c])
__global__ void gcn_spmm(const int* __restrict__ iptr, const int* __restrict__ isrc,
                         const float* __restrict__ Z, const float* __restrict__ dinv,
                         const float* __restrict__ bias, float* __restrict__ outp, int C) {
  int i = blockIdx.x;
  int c = threadIdx.x;
  float acc = Z[(size_t)i * C + c];
  int beg = iptr[i], end = iptr[i + 1];
  for (int e = beg; e < end; ++e) acc += Z[(size_t)isrc[e] * C + c];
  outp[(size_t)i * C + c] = fmaxf(dinv[i] * acc + bias[c], 0.f);
}

// ---------------- launcher ----------------
extern "C" void kernel_launch(void* const* d_in, const int* in_sizes, int n_in,
                              void* d_out, int out_size, void* d_ws, size_t ws_size,
                              hipStream_t stream) {
  const float* x      = (const float*)d_in[0];
  const int*   eidx   = (const int*)d_in[1];
  const float* theta0 = (const float*)d_in[2];
  const float* b0     = (const float*)d_in[3];
  const float* theta1 = (const float*)d_in[4];
  const float* b1     = (const float*)d_in[5];
  const float* theta2 = (const float*)d_in[6];
  const float* b2     = (const float*)d_in[7];
  const float* theta3 = (const float*)d_in[8];
  const float* b3     = (const float*)d_in[9];
  const float* theta4 = (const float*)d_in[10];
  const float* b4     = (const float*)d_in[11];
  const float* p1     = (const float*)d_in[12];
  const float* p2     = (const float*)d_in[13];
  const int E = in_sizes[1] / 2;
  const int* src = eidx;
  const int* dst = eidx + E;
  float* out = (float*)d_out;

  char* wsb = (char*)d_ws;
  size_t off = 0;
  auto alloc = [&](size_t bytes) -> void* {
    void* p = wsb + off;
    off = (off + bytes + 255) & ~(size_t)255;
    return p;
  };
  int* optr  = (int*)alloc((N0 + 1) * 4);
  int* iptr  = (int*)alloc((N0 + 1) * 4);
  int* odst  = (int*)alloc((size_t)E * 4);
  int* isrc  = (int*)alloc((size_t)E * 4);
  int* cnt4  = (int*)alloc((size_t)4 * N0 * 4);  // co, ci, fo, fi
  int* perm1 = (int*)alloc(P1K * 4);
  int* rank1 = (int*)alloc(N0 * 4);
  int* perm2 = (int*)alloc(P2K * 4);
  int* rank2 = (int*)alloc(P1K * 4);
  float* dinv0 = (float*)alloc(N0 * 4);
  float* dinv1 = (float*)alloc(P1K * 4);
  float* dinv2 = (float*)alloc(P2K * 4);
  float* vals1 = (float*)alloc(P1K * 4);
  float* vals2 = (float*)alloc(P2K * 4);
  float* score = (float*)alloc(N0 * 4);
  float* x0  = (float*)alloc((size_t)N0 * 256 * 4);
  float* x1  = (float*)alloc((size_t)P1K * 256 * 4);
  float* x1b = (float*)alloc((size_t)P1K * 512 * 4);
  float* x2  = (float*)alloc((size_t)P2K * 512 * 4);
  float* xb  = (float*)alloc((size_t)P2K * 512 * 4);
  float* xu  = (float*)alloc((size_t)P1K * 256 * 4);
  float* SA  = (float*)alloc((size_t)1048576 * 4);  // xt/Z scratch (max 4096x256 / 2048x512)
  float* SC  = (float*)alloc((size_t)1048576 * 4);  // Y scratch
  float* W1  = (float*)alloc((size_t)P1K * P1K * 4);
  float* W2  = (float*)alloc((size_t)P2K * P2K * 4);
  (void)ws_size; (void)n_in; (void)out_size;

  int* co = cnt4;
  int* ci = cnt4 + N0;
  int* fo = cnt4 + 2 * N0;
  int* fi = cnt4 + 3 * N0;

  // --- graph build ---
  hipMemsetAsync(cnt4, 0, (size_t)4 * N0 * 4, stream);
  count_edges<<<E / 256, 256, 0, stream>>>(src, dst, co, ci, E);
  exscan4096<<<1, 1024, 0, stream>>>(co, optr);
  exscan4096<<<1, 1024, 0, stream>>>(ci, iptr);
  fill_edges<<<E / 256, 256, 0, stream>>>(src, dst, optr, iptr, fo, fi, odst, isrc, E);
  dinv0_kernel<<<N0 / 256, 256, 0, stream>>>(optr, dinv0);

  // --- gcn0: x[4096,128] -> x0[4096,256] ---
  mm_kernel<false><<<(4096 / 64) * (256 / 64), 256, 0, stream>>>(x, theta0, SA, 4096, 256, 128);
  scale_rows<<<4096 * 256 / 256, 256, 0, stream>>>(SA, dinv0, 256, 4096 * 256);
  gcn_spmm<<<4096, 256, 0, stream>>>(iptr, isrc, SA, dinv0, b0, x0, 256);

  // --- pool 1 ---
  score_kernel<<<4096, 256, 0, stream>>>(x0, 256, p1, score);
  topk_kernel<<<1, 1024, 0, stream>>>(score, 4096, 2048, perm1, vals1, rank1);
  gather_scale<<<2048 * 256 / 256, 256, 0, stream>>>(x0, perm1, vals1, x1, 256, 2048 * 256);
  build_W1<<<2048, 256, 0, stream>>>(optr, odst, perm1, rank1, W1, dinv1);

  // --- gcn1: x1[2048,256] -> x1b[2048,512] ---
  mm_kernel<false><<<(2048 / 64) * (512 / 64), 256, 0, stream>>>(x1, theta1, SA, 2048, 512, 256);
  scale_rows<<<2048 * 512 / 256, 256, 0, stream>>>(SA, dinv1, 512, 2048 * 512);
  mm_kernel<true><<<(2048 / 64) * (512 / 64), 256, 0, stream>>>(W1, SA, SC, 2048, 512, 2048);
  gcn_epi<<<2048 * 512 / 256, 256, 0, stream>>>(SC, SA, dinv1, b1, x1b, 512, 2048 * 512);

  // --- pool 2 ---
  score_kernel<<<2048, 256, 0, stream>>>(x1b, 512, p2, score);
  topk_kernel<<<1, 1024, 0, stream>>>(score, 2048, 1024, perm2, vals2, rank2);
  gather_scale<<<1024 * 512 / 256, 256, 0, stream>>>(x1b, perm2, vals2, x2, 512, 1024 * 512);
  mm_w2<<<16 * 16, 256, 0, stream>>>(W1, perm2, W2);
  postW2<<<1024, 256, 0, stream>>>(W2, dinv2);

  // --- gcn2 (bottleneck): x2[1024,512] -> xb[1024,512] ---
  mm_kernel<false><<<(1024 / 64) * (512 / 64), 256, 0, stream>>>(x2, theta2, SA, 1024, 512, 512);
  scale_rows<<<1024 * 512 / 256, 256, 0, stream>>>(SA, dinv2, 512, 1024 * 512);
  mm_kernel<true><<<(1024 / 64) * (512 / 64), 256, 0, stream>>>(W2, SA, SC, 1024, 512, 1024);
  gcn_epi<<<1024 * 512 / 256, 256, 0, stream>>>(SC, SA, dinv2, b2, xb, 512, 1024 * 512);
  mean_cols<<<512, 256, 0, stream>>>(xb, 1024, 512, out + 524288);

  // --- up block 1: in3 = x1b + scatter(xb) (in-place), -> xu[2048,256] ---
  add_up<<<2048 * 512 / 256, 256, 0, stream>>>(x1b, rank2, xb, x1b, 512, 2048 * 512);
  mm_kernel<false><<<(2048 / 64) * (256 / 64), 256, 0, stream>>>(x1b, theta3, SA, 2048, 256, 512);
  scale_rows<<<2048 * 256 / 256, 256, 0, stream>>>(SA, dinv1, 256, 2048 * 256);
  mm_kernel<true><<<(2048 / 64) * (256 / 64), 256, 0, stream>>>(W1, SA, SC, 2048, 256, 2048);
  gcn_epi<<<2048 * 256 / 256, 256, 0, stream>>>(SC, SA, dinv1, b3, xu, 256, 2048 * 256);

  // --- up block 0: in4 = x0 + scatter(xu) (in-place), -> out[4096,128] ---
  add_up<<<4096 * 256 / 256, 256, 0, stream>>>(x0, rank1, xu, x0, 256, 4096 * 256);
  mm_kernel<false><<<(4096 / 64) * (128 / 64), 256, 0, stream>>>(x0, theta4, SA, 4096, 128, 256);
  scale_rows<<<4096 * 128 / 256, 256, 0, stream>>>(SA, dinv0, 128, 4096 * 128);
  gcn_spmm<<<4096, 128, 0, stream>>>(iptr, isrc, SA, dinv0, b4, out, 128);
}

// Round 2
// 703.902 us; speedup vs baseline: 1.2438x; 1.2438x over previous
//
#include <hip/hip_runtime.h>

#define N0 4096
#define P1K 2048
#define P2K 1024

typedef short bf16x8 __attribute__((ext_vector_type(8)));
typedef float f32x4 __attribute__((ext_vector_type(4)));

__device__ __forceinline__ unsigned short f2bf(float f) {
  unsigned int u = __float_as_uint(f);
  unsigned int r = (u + 0x7fff + ((u >> 16) & 1)) >> 16;
  return (unsigned short)r;
}
__device__ __forceinline__ float bf2f(unsigned short h) {
  unsigned int u = ((unsigned int)h) << 16;
  return __uint_as_float(u);
}

// ---------------- helpers ----------------
__device__ __forceinline__ float blockReduceSum256(float v) {
  __shared__ float sh[16];
  int lane = threadIdx.x & 63;
  int w = threadIdx.x >> 6;
#pragma unroll
  for (int o = 32; o > 0; o >>= 1) v += __shfl_down(v, o, 64);
  __syncthreads();
  if (lane == 0) sh[w] = v;
  __syncthreads();
  float r = 0.f;
  if (threadIdx.x == 0) {
    int nw = (blockDim.x + 63) >> 6;
    for (int i = 0; i < nw; ++i) r += sh[i];
  }
  return r;  // valid on thread 0 only
}

// ---------------- graph build ----------------
__global__ void count_edges(const int* __restrict__ src, const int* __restrict__ dst,
                            int* __restrict__ co, int* __restrict__ ci, int E) {
  int e = blockIdx.x * blockDim.x + threadIdx.x;
  if (e >= E) return;
  atomicAdd(&co[src[e]], 1);
  atomicAdd(&ci[dst[e]], 1);
}

__global__ __launch_bounds__(1024) void exscan4096(const int* __restrict__ cnt,
                                                   int* __restrict__ ptr) {
  __shared__ int ls[1024];
  int t = threadIdx.x;
  int v0 = cnt[t * 4], v1 = cnt[t * 4 + 1], v2 = cnt[t * 4 + 2], v3 = cnt[t * 4 + 3];
  int s = v0 + v1 + v2 + v3;
  ls[t] = s;
  __syncthreads();
  for (int off = 1; off < 1024; off <<= 1) {
    int x = (t >= off) ? ls[t - off] : 0;
    __syncthreads();
    ls[t] += x;
    __syncthreads();
  }
  int ex = (t > 0) ? ls[t - 1] : 0;
  ptr[t * 4]     = ex;
  ptr[t * 4 + 1] = ex + v0;
  ptr[t * 4 + 2] = ex + v0 + v1;
  ptr[t * 4 + 3] = ex + v0 + v1 + v2;
  if (t == 1023) ptr[4096] = ex + s;
}

__global__ void fill_edges(const int* __restrict__ src, const int* __restrict__ dst,
                           const int* __restrict__ optr, const int* __restrict__ iptr,
                           int* __restrict__ fo, int* __restrict__ fi,
                           int* __restrict__ odst, int* __restrict__ isrc, int E) {
  int e = blockIdx.x * blockDim.x + threadIdx.x;
  if (e >= E) return;
  int s = src[e], d = dst[e];
  odst[optr[s] + atomicAdd(&fo[s], 1)] = d;
  isrc[iptr[d] + atomicAdd(&fi[d], 1)] = s;
}

__global__ void dinv0_kernel(const int* __restrict__ optr, float* __restrict__ dinv0) {
  int i = blockIdx.x * blockDim.x + threadIdx.x;
  if (i < N0) dinv0[i] = rsqrtf((float)(optr[i + 1] - optr[i]) + 1.0f);
}

// diag(A^2)[i], A = W + I, integer-exact 2-hop count of paths i->k->i. One wave/node.
__global__ __launch_bounds__(64) void diag2_kernel(const int* __restrict__ optr,
                                                   const int* __restrict__ odst,
                                                   float* __restrict__ diag2) {
  int i = blockIdx.x;
  int cnt = 0;
  int kbeg = optr[i], kend = optr[i + 1];
  for (int kk = kbeg - 1; kk < kend; ++kk) {
    int k = (kk < kbeg) ? i : odst[kk];
    int jbeg = optr[k], jend = optr[k + 1];
    for (int jj = jbeg - 1 + (int)threadIdx.x; jj < jend; jj += 64) {
      int j = (jj < jbeg) ? k : odst[jj];
      if (j == i) cnt++;
    }
  }
#pragma unroll
  for (int o = 32; o > 0; o >>= 1) cnt += __shfl_down(cnt, o, 64);
  if (threadIdx.x == 0) diag2[i] = (float)cnt;
}

// ---------------- dense matmul: C[M,N] = A@B (TA=0) or A^T@B (TA=1, A is [K,M]) ----
template <bool TRANS_A>
__global__ void mm_kernel(const float* __restrict__ A, const float* __restrict__ B,
                          float* __restrict__ C, int M, int N, int K) {
  __shared__ float As[16][64];
  __shared__ float Bs[16][64];
  int tid = threadIdx.x;
  int nbx = N >> 6;
  int by = blockIdx.x / nbx, bx = blockIdx.x % nbx;
  int row0 = by << 6, col0 = bx << 6;
  int tx = tid & 15, ty = tid >> 4;
  float acc[4][4] = {{0.f}};
  for (int k0 = 0; k0 < K; k0 += 16) {
    if (TRANS_A) {
#pragma unroll
      for (int p = 0; p < 4; ++p) {
        int kk = (tid >> 6) + (p << 2);
        int i = tid & 63;
        As[kk][i] = A[(size_t)(k0 + kk) * M + row0 + i];
      }
    } else {
#pragma unroll
      for (int p = 0; p < 4; ++p) {
        int r = (tid >> 4) + (p << 4);
        int kk = tid & 15;
        As[kk][r] = A[(size_t)(row0 + r) * K + k0 + kk];
      }
    }
#pragma unroll
    for (int p = 0; p < 4; ++p) {
      int kk = (tid >> 6) + (p << 2);
      int c = tid & 63;
      Bs[kk][c] = B[(size_t)(k0 + kk) * N + col0 + c];
    }
    __syncthreads();
#pragma unroll
    for (int kk = 0; kk < 16; ++kk) {
      float a[4], b[4];
#pragma unroll
      for (int i = 0; i < 4; ++i) a[i] = As[kk][(ty << 2) + i];
#pragma unroll
      for (int j = 0; j < 4; ++j) b[j] = Bs[kk][(tx << 2) + j];
#pragma unroll
      for (int i = 0; i < 4; ++i)
#pragma unroll
        for (int j = 0; j < 4; ++j) acc[i][j] += a[i] * b[j];
    }
    __syncthreads();
  }
#pragma unroll
  for (int i = 0; i < 4; ++i) {
    int r = row0 + (ty << 2) + i;
#pragma unroll
    for (int j = 0; j < 4; ++j) C[(size_t)r * N + col0 + (tx << 2) + j] = acc[i][j];
  }
}

// ---------------- W2 = A1[p2,:] @ A1[:,p2] via bf16 MFMA (integer-exact) ----------
// Wb = W1 bf16 [2048][2048], WbT = its transpose. A1 = W1 + I handled by +1 fixups.
__global__ __launch_bounds__(256) void mm_w2_mfma(const unsigned short* __restrict__ Wb,
                                                  const unsigned short* __restrict__ WbT,
                                                  const int* __restrict__ perm2,
                                                  float* __restrict__ W2) {
  __shared__ unsigned short As[64 * 64];  // [row][k], 16B chunks XOR-swizzled by row&7
  __shared__ unsigned short Bs[64 * 64];  // [col][k], same swizzle
  __shared__ int pr[64], pc[64];
  int tid = threadIdx.x;
  int bx = blockIdx.x & 15, by = blockIdx.x >> 4;
  int row0 = by << 6, col0 = bx << 6;
  if (tid < 64) pr[tid] = perm2[row0 + tid];
  else if (tid < 128) pc[tid - 64] = perm2[col0 + tid - 128 + 64];
  __syncthreads();
  int l = tid & 63, wv = tid >> 6;
  int wr = (wv >> 1) << 5, wc = (wv & 1) << 5;
  f32x4 acc[2][2] = {};
  for (int k0 = 0; k0 < 2048; k0 += 64) {
#pragma unroll
    for (int it = 0; it < 2; ++it) {
      int idx = (it << 8) + tid;
      int r = idx >> 3, c8 = idx & 7;
      int sw = c8 ^ (r & 7);
      ((uint4*)As)[(r << 3) + sw] =
          *(const uint4*)(Wb + (size_t)pr[r] * 2048 + k0 + (c8 << 3));
      ((uint4*)Bs)[(r << 3) + sw] =
          *(const uint4*)(WbT + (size_t)pc[r] * 2048 + k0 + (c8 << 3));
    }
    __syncthreads();
    // +I fixups (A1 = W1 + I)
    if (tid < 64) {
      int r = tid, d = pr[r] - k0;
      if (d >= 0 && d < 64) {
        int ui = (r << 6) + (((d >> 3) ^ (r & 7)) << 3) + (d & 7);
        As[ui] = f2bf(bf2f(As[ui]) + 1.f);
      }
    } else if (tid < 128) {
      int c = tid - 64, d = pc[c] - k0;
      if (d >= 0 && d < 64) {
        int ui = (c << 6) + (((d >> 3) ^ (c & 7)) << 3) + (d & 7);
        Bs[ui] = f2bf(bf2f(Bs[ui]) + 1.f);
      }
    }
    __syncthreads();
#pragma unroll
    for (int kk2 = 0; kk2 < 2; ++kk2) {
      int ch = (kk2 << 2) + (l >> 4);
      int ra = wr + (l & 15), rb = ra + 16;
      int ca = wc + (l & 15), cb = ca + 16;
      bf16x8 a0 = *(const bf16x8*)&As[(ra << 6) + ((ch ^ (ra & 7)) << 3)];
      bf16x8 a1 = *(const bf16x8*)&As[(rb << 6) + ((ch ^ (rb & 7)) << 3)];
      bf16x8 b0 = *(const bf16x8*)&Bs[(ca << 6) + ((ch ^ (ca & 7)) << 3)];
      bf16x8 b1 = *(const bf16x8*)&Bs[(cb << 6) + ((ch ^ (cb & 7)) << 3)];
      acc[0][0] = __builtin_amdgcn_mfma_f32_16x16x32_bf16(a0, b0, acc[0][0], 0, 0, 0);
      acc[0][1] = __builtin_amdgcn_mfma_f32_16x16x32_bf16(a0, b1, acc[0][1], 0, 0, 0);
      acc[1][0] = __builtin_amdgcn_mfma_f32_16x16x32_bf16(a1, b0, acc[1][0], 0, 0, 0);
      acc[1][1] = __builtin_amdgcn_mfma_f32_16x16x32_bf16(a1, b1, acc[1][1], 0, 0, 0);
    }
    __syncthreads();
  }
  int lrow = (l >> 4) << 2, lcol = l & 15;
#pragma unroll
  for (int i = 0; i < 2; ++i)
#pragma unroll
    for (int j = 0; j < 2; ++j)
#pragma unroll
      for (int rg = 0; rg < 4; ++rg) {
        int r = row0 + wr + (i << 4) + lrow + rg;
        int c = col0 + wc + (j << 4) + lcol;
        W2[(size_t)r * 1024 + c] = acc[i][j][rg];
      }
}

// 64x64-tile bf16 transpose
__global__ __launch_bounds__(256) void transpose_bf16(const unsigned short* __restrict__ in,
                                                      unsigned short* __restrict__ out,
                                                      int n) {
  __shared__ unsigned short t[64][65];
  int nb = n >> 6;
  int bx = blockIdx.x % nb, by = blockIdx.x / nb;
  int r0 = by << 6, c0 = bx << 6;
  for (int it = 0; it < 16; ++it) {
    int idx = (it << 8) + threadIdx.x;
    int r = idx >> 6, c = idx & 63;
    t[r][c] = in[(size_t)(r0 + r) * n + c0 + c];
  }
  __syncthreads();
  for (int it = 0; it < 16; ++it) {
    int idx = (it << 8) + threadIdx.x;
    int r = idx >> 6, c = idx & 63;
    out[(size_t)(c0 + r) * n + r0 + c] = t[c][r];
  }
}

// ---------------- elementwise / epilogues ----------------
__global__ void scale_rows(float* __restrict__ Z, const float* __restrict__ dinv,
                           int C, int total) {
  int idx = blockIdx.x * blockDim.x + threadIdx.x;
  if (idx >= total) return;
  Z[idx] *= dinv[idx / C];
}

__global__ void gcn_epi(const float* __restrict__ Y, const float* __restrict__ Z,
                        const float* __restrict__ dinv, const float* __restrict__ bias,
                        float* __restrict__ outp, int C, int total) {
  int idx = blockIdx.x * blockDim.x + threadIdx.x;
  if (idx >= total) return;
  int i = idx / C, c = idx % C;
  outp[idx] = fmaxf(dinv[i] * (Y[idx] + Z[idx]) + bias[c], 0.f);
}

// out[r,c] = relu(dinv[r]*(U2[p[r],c] + (1-diag2[p[r]])*Z[r,c]) + b[c])
__global__ void gcn_epi_sparse(const float* __restrict__ U2, const int* __restrict__ perm,
                               const float* __restrict__ diag2, const float* __restrict__ Z,
                               const float* __restrict__ dinv, const float* __restrict__ bias,
                               float* __restrict__ outp, int C, int total) {
  int idx = blockIdx.x * blockDim.x + threadIdx.x;
  if (idx >= total) return;
  int r = idx / C, c = idx % C;
  int p = perm[r];
  float v = U2[(size_t)p * C + c] + (1.f - diag2[p]) * Z[idx];
  outp[idx] = fmaxf(dinv[r] * v + bias[c], 0.f);
}

__global__ void scatter_full(const float* __restrict__ Z, const int* __restrict__ rank,
                             float* __restrict__ Zf, int C, int total) {
  int idx = blockIdx.x * blockDim.x + threadIdx.x;
  if (idx >= total) return;
  int n = idx / C, c = idx % C;
  int r = rank[n];
  Zf[idx] = (r >= 0) ? Z[(size_t)r * C + c] : 0.f;
}

// u[i,:] = Zin[i,:] + sum_{in-edges e of i} Zin[isrc[e],:]   (= (W+I)^T Zin row i)
__global__ void atspmm(const int* __restrict__ iptr, const int* __restrict__ isrc,
                       const float* __restrict__ Zin, float* __restrict__ Zout, int C) {
  int i = blockIdx.x;
  int beg = iptr[i], end = iptr[i + 1];
  for (int c = threadIdx.x; c < C; c += blockDim.x) {
    float acc = Zin[(size_t)i * C + c];
    for (int e = beg; e < end; ++e) acc += Zin[(size_t)isrc[e] * C + c];
    Zout[(size_t)i * C + c] = acc;
  }
}

__global__ void gather_scale(const float* __restrict__ X, const int* __restrict__ perm,
                             const float* __restrict__ vals, float* __restrict__ outp,
                             int C, int total) {
  int idx = blockIdx.x * blockDim.x + threadIdx.x;
  if (idx >= total) return;
  int a = idx / C, c = idx % C;
  outp[idx] = X[(size_t)perm[a] * C + c] * vals[a];
}

// out = base + scatter(up) via rank (in-place safe)
__global__ void add_up(const float* base, const int* __restrict__ rank,
                       const float* __restrict__ up, float* outp, int C, int total) {
  int idx = blockIdx.x * blockDim.x + threadIdx.x;
  if (idx >= total) return;
  int r = idx / C, c = idx % C;
  int rk = rank[r];
  float v = base[idx];
  if (rk >= 0) v += up[(size_t)rk * C + c];
  outp[idx] = v;
}

__global__ void score_kernel(const float* __restrict__ X, int C,
                             const float* __restrict__ p, float* __restrict__ sc) {
  int i = blockIdx.x;
  float s1 = 0.f, s2 = 0.f;
  for (int c = threadIdx.x; c < C; c += blockDim.x) {
    float pv = p[c];
    s1 += pv * pv;
    s2 += X[(size_t)i * C + c] * pv;
  }
  float r1 = blockReduceSum256(s1);
  __syncthreads();
  float r2 = blockReduceSum256(s2);
  if (threadIdx.x == 0) sc[i] = tanhf(r2 / sqrtf(r1));
}

__global__ __launch_bounds__(1024) void topk_kernel(const float* __restrict__ score, int n,
                                                    int k, int* __restrict__ perm,
                                                    float* __restrict__ vals,
                                                    int* __restrict__ rank) {
  __shared__ float s[4096];
  __shared__ int id[4096];
  for (int i = threadIdx.x; i < n; i += blockDim.x) { s[i] = score[i]; id[i] = i; }
  __syncthreads();
  for (int size = 2; size <= n; size <<= 1) {
    for (int stride = size >> 1; stride > 0; stride >>= 1) {
      for (int i = threadIdx.x; i < n; i += blockDim.x) {
        int j = i ^ stride;
        if (j > i) {
          float si = s[i], sj = s[j];
          int ii = id[i], ij = id[j];
          bool iFirst = (si > sj) || (si == sj && ii < ij);
          bool up = ((i & size) == 0);
          if (up ? !iFirst : iFirst) { s[i] = sj; s[j] = si; id[i] = ij; id[j] = ii; }
        }
      }
      __syncthreads();
    }
  }
  for (int t = threadIdx.x; t < n; t += blockDim.x) {
    int node = id[t];
    rank[node] = (t < k) ? t : -1;
    if (t < k) { perm[t] = node; vals[t] = s[t]; }
  }
}

// W1[a,b] (bf16, integer-exact) + dinv1; W1 = A^2[p1,p1] with diag removed
__global__ void build_W1(const int* __restrict__ optr, const int* __restrict__ odst,
                         const int* __restrict__ perm1, const int* __restrict__ rank1,
                         unsigned short* __restrict__ W1b, float* __restrict__ dinv1) {
  __shared__ float row[2048];
  int a = blockIdx.x;
  int pa = perm1[a];
  for (int i = threadIdx.x; i < 2048; i += blockDim.x) row[i] = 0.f;
  __syncthreads();
  int kbeg = optr[pa], kend = optr[pa + 1];
  for (int kk = kbeg - 1; kk < kend; ++kk) {
    int k = (kk < kbeg) ? pa : odst[kk];
    int jbeg = optr[k], jend = optr[k + 1];
    for (int jj = jbeg - 1 + (int)threadIdx.x; jj < jend; jj += (int)blockDim.x) {
      int j = (jj < jbeg) ? k : odst[jj];
      int rb = rank1[j];
      if (rb >= 0) atomicAdd(&row[rb], 1.0f);
    }
  }
  __syncthreads();
  float ssum = 0.f;
  for (int i = threadIdx.x; i < 2048; i += blockDim.x) {
    float v = (i == a) ? 0.f : row[i];
    W1b[(size_t)a * 2048 + i] = f2bf(v);
    ssum += v;
  }
  float t = blockReduceSum256(ssum);
  if (threadIdx.x == 0) dinv1[a] = rsqrtf(t + 1.0f);
}

__global__ void postW2(float* __restrict__ W2, float* __restrict__ dinv2) {
  int a = blockIdx.x;
  float ssum = 0.f;
  for (int i = threadIdx.x; i < 1024; i += blockDim.x) {
    float v = W2[(size_t)a * 1024 + i];
    if (i == a) { W2[(size_t)a * 1024 + i] = 0.f; v = 0.f; }
    ssum += v;
  }
  float t = blockReduceSum256(ssum);
  if (threadIdx.x == 0) dinv2[a] = rsqrtf(t + 1.0f);
}

__global__ void mean_cols(const float* __restrict__ X, int R, int C, float* __restrict__ outp) {
  int c = blockIdx.x;
  float s = 0.f;
  for (int r = threadIdx.x; r < R; r += blockDim.x) s += X[(size_t)r * C + c];
  float t = blockReduceSum256(s);
  if (threadIdx.x == 0) outp[c] = t / (float)R;
}

__global__ void gcn_spmm(const int* __restrict__ iptr, const int* __restrict__ isrc,
                         const float* __restrict__ Z, const float* __restrict__ dinv,
                         const float* __restrict__ bias, float* __restrict__ outp, int C) {
  int i = blockIdx.x;
  int c = threadIdx.x;
  float acc = Z[(size_t)i * C + c];
  int beg = iptr[i], end = iptr[i + 1];
  for (int e = beg; e < end; ++e) acc += Z[(size_t)isrc[e] * C + c];
  outp[(size_t)i * C + c] = fmaxf(dinv[i] * acc + bias[c], 0.f);
}

// ---------------- launcher ----------------
extern "C" void kernel_launch(void* const* d_in, const int* in_sizes, int n_in,
                              void* d_out, int out_size, void* d_ws, size_t ws_size,
                              hipStream_t stream) {
  const float* x      = (const float*)d_in[0];
  const int*   eidx   = (const int*)d_in[1];
  const float* theta0 = (const float*)d_in[2];
  const float* b0     = (const float*)d_in[3];
  const float* theta1 = (const float*)d_in[4];
  const float* b1     = (const float*)d_in[5];
  const float* theta2 = (const float*)d_in[6];
  const float* b2     = (const float*)d_in[7];
  const float* theta3 = (const float*)d_in[8];
  const float* b3     = (const float*)d_in[9];
  const float* theta4 = (const float*)d_in[10];
  const float* b4     = (const float*)d_in[11];
  const float* p1     = (const float*)d_in[12];
  const float* p2     = (const float*)d_in[13];
  const int E = in_sizes[1] / 2;
  const int* src = eidx;
  const int* dst = eidx + E;
  float* out = (float*)d_out;

  char* wsb = (char*)d_ws;
  size_t off = 0;
  auto alloc = [&](size_t bytes) -> void* {
    void* p = wsb + off;
    off = (off + bytes + 255) & ~(size_t)255;
    return p;
  };
  int* optr  = (int*)alloc((N0 + 1) * 4);
  int* iptr  = (int*)alloc((N0 + 1) * 4);
  int* odst  = (int*)alloc((size_t)E * 4);
  int* isrc  = (int*)alloc((size_t)E * 4);
  int* cnt4  = (int*)alloc((size_t)4 * N0 * 4);
  int* perm1 = (int*)alloc(P1K * 4);
  int* rank1 = (int*)alloc(N0 * 4);
  int* perm2 = (int*)alloc(P2K * 4);
  int* rank2 = (int*)alloc(P1K * 4);
  float* dinv0 = (float*)alloc(N0 * 4);
  float* dinv1 = (float*)alloc(P1K * 4);
  float* dinv2 = (float*)alloc(P2K * 4);
  float* vals1 = (float*)alloc(P1K * 4);
  float* vals2 = (float*)alloc(P2K * 4);
  float* score = (float*)alloc(N0 * 4);
  float* diag2 = (float*)alloc(N0 * 4);
  float* x0  = (float*)alloc((size_t)N0 * 256 * 4);
  float* x1  = (float*)alloc((size_t)P1K * 256 * 4);
  float* x1b = (float*)alloc((size_t)P1K * 512 * 4);
  float* x2  = (float*)alloc((size_t)P2K * 512 * 4);
  float* xb  = (float*)alloc((size_t)P2K * 512 * 4);
  float* xu  = (float*)alloc((size_t)P1K * 256 * 4);
  float* SA  = (float*)alloc((size_t)P1K * 512 * 4);       // Z scratch
  float* SC  = (float*)alloc((size_t)P2K * 512 * 4);       // gcn2 Y scratch
  float* ZF  = (float*)alloc((size_t)N0 * 512 * 4);        // full scatter / U2
  float* ZU  = (float*)alloc((size_t)N0 * 512 * 4);        // U1
  unsigned short* W1b  = (unsigned short*)alloc((size_t)P1K * P1K * 2);
  unsigned short* W1bT = (unsigned short*)alloc((size_t)P1K * P1K * 2);
  float* W2  = (float*)alloc((size_t)P2K * P2K * 4);
  (void)ws_size; (void)n_in; (void)out_size;

  int* co = cnt4;
  int* ci = cnt4 + N0;
  int* fo = cnt4 + 2 * N0;
  int* fi = cnt4 + 3 * N0;

  // --- graph build ---
  hipMemsetAsync(cnt4, 0, (size_t)4 * N0 * 4, stream);
  count_edges<<<E / 256, 256, 0, stream>>>(src, dst, co, ci, E);
  exscan4096<<<1, 1024, 0, stream>>>(co, optr);
  exscan4096<<<1, 1024, 0, stream>>>(ci, iptr);
  fill_edges<<<E / 256, 256, 0, stream>>>(src, dst, optr, iptr, fo, fi, odst, isrc, E);
  dinv0_kernel<<<N0 / 256, 256, 0, stream>>>(optr, dinv0);
  diag2_kernel<<<N0, 64, 0, stream>>>(optr, odst, diag2);

  // --- gcn0: x[4096,128] -> x0[4096,256] ---
  mm_kernel<false><<<(4096 / 64) * (256 / 64), 256, 0, stream>>>(x, theta0, SA, 4096, 256, 128);
  scale_rows<<<4096 * 256 / 256, 256, 0, stream>>>(SA, dinv0, 256, 4096 * 256);
  gcn_spmm<<<4096, 256, 0, stream>>>(iptr, isrc, SA, dinv0, b0, x0, 256);

  // --- pool 1 ---
  score_kernel<<<4096, 256, 0, stream>>>(x0, 256, p1, score);
  topk_kernel<<<1, 1024, 0, stream>>>(score, 4096, 2048, perm1, vals1, rank1);
  gather_scale<<<2048 * 256 / 256, 256, 0, stream>>>(x0, perm1, vals1, x1, 256, 2048 * 256);
  build_W1<<<2048, 256, 0, stream>>>(optr, odst, perm1, rank1, W1b, dinv1);
  transpose_bf16<<<(2048 / 64) * (2048 / 64), 256, 0, stream>>>(W1b, W1bT, 2048);

  // --- gcn1 (sparse 2-hop agg): x1[2048,256] -> x1b[2048,512] ---
  mm_kernel<false><<<(2048 / 64) * (512 / 64), 256, 0, stream>>>(x1, theta1, SA, 2048, 512, 256);
  scale_rows<<<2048 * 512 / 256, 256, 0, stream>>>(SA, dinv1, 512, 2048 * 512);
  scatter_full<<<4096 * 512 / 256, 256, 0, stream>>>(SA, rank1, ZF, 512, 4096 * 512);
  atspmm<<<4096, 256, 0, stream>>>(iptr, isrc, ZF, ZU, 512);
  atspmm<<<4096, 256, 0, stream>>>(iptr, isrc, ZU, ZF, 512);
  gcn_epi_sparse<<<2048 * 512 / 256, 256, 0, stream>>>(ZF, perm1, diag2, SA, dinv1, b1,
                                                       x1b, 512, 2048 * 512);

  // --- pool 2 ---
  score_kernel<<<2048, 256, 0, stream>>>(x1b, 512, p2, score);
  topk_kernel<<<1, 1024, 0, stream>>>(score, 2048, 1024, perm2, vals2, rank2);
  gather_scale<<<1024 * 512 / 256, 256, 0, stream>>>(x1b, perm2, vals2, x2, 512, 1024 * 512);
  mm_w2_mfma<<<16 * 16, 256, 0, stream>>>(W1b, W1bT, perm2, W2);
  postW2<<<1024, 256, 0, stream>>>(W2, dinv2);

  // --- gcn2 (bottleneck): x2[1024,512] -> xb[1024,512] ---
  mm_kernel<false><<<(1024 / 64) * (512 / 64), 256, 0, stream>>>(x2, theta2, SA, 1024, 512, 512);
  scale_rows<<<1024 * 512 / 256, 256, 0, stream>>>(SA, dinv2, 512, 1024 * 512);
  mm_kernel<true><<<(1024 / 64) * (512 / 64), 256, 0, stream>>>(W2, SA, SC, 1024, 512, 1024);
  gcn_epi<<<1024 * 512 / 256, 256, 0, stream>>>(SC, SA, dinv2, b2, xb, 512, 1024 * 512);
  mean_cols<<<512, 256, 0, stream>>>(xb, 1024, 512, out + 524288);

  // --- up block 1 (sparse 2-hop agg): -> xu[2048,256] ---
  add_up<<<2048 * 512 / 256, 256, 0, stream>>>(x1b, rank2, xb, x1b, 512, 2048 * 512);
  mm_kernel<false><<<(2048 / 64) * (256 / 64), 256, 0, stream>>>(x1b, theta3, SA, 2048, 256, 512);
  scale_rows<<<2048 * 256 / 256, 256, 0, stream>>>(SA, dinv1, 256, 2048 * 256);
  scatter_full<<<4096 * 256 / 256, 256, 0, stream>>>(SA, rank1, ZF, 256, 4096 * 256);
  atspmm<<<4096, 256, 0, stream>>>(iptr, isrc, ZF, ZU, 256);
  atspmm<<<4096, 256, 0, stream>>>(iptr, isrc, ZU, ZF, 256);
  gcn_epi_sparse<<<2048 * 256 / 256, 256, 0, stream>>>(ZF, perm1, diag2, SA, dinv1, b3,
                                                       xu, 256, 2048 * 256);

  // --- up block 0: -> out[4096,128] ---
  add_up<<<4096 * 256 / 256, 256, 0, stream>>>(x0, rank1, xu, x0, 256, 4096 * 256);
  mm_kernel<false><<<(4096 / 64) * (128 / 64), 256, 0, stream>>>(x0, theta4, SA, 4096, 128, 256);
  scale_rows<<<4096 * 128 / 256, 256, 0, stream>>>(SA, dinv0, 128, 4096 * 128);
  gcn_spmm<<<4096, 128, 0, stream>>>(iptr, isrc, SA, dinv0, b4, out, 128);
}

// Round 3
// 570.997 us; speedup vs baseline: 1.5333x; 1.2328x over previous
//
#include <hip/hip_runtime.h>

#define N0 4096
#define P1K 2048
#define P2K 1024

typedef short bf16x8 __attribute__((ext_vector_type(8)));
typedef float f32x4 __attribute__((ext_vector_type(4)));

__device__ __forceinline__ unsigned short f2bf(float f) {
  unsigned int u = __float_as_uint(f);
  unsigned int r = (u + 0x7fff + ((u >> 16) & 1)) >> 16;
  return (unsigned short)r;
}
__device__ __forceinline__ float bf2f(unsigned short h) {
  unsigned int u = ((unsigned int)h) << 16;
  return __uint_as_float(u);
}

// ---------------- helpers ----------------
__device__ __forceinline__ float blockReduceSum256(float v) {
  __shared__ float sh[16];
  int lane = threadIdx.x & 63;
  int w = threadIdx.x >> 6;
#pragma unroll
  for (int o = 32; o > 0; o >>= 1) v += __shfl_down(v, o, 64);
  __syncthreads();
  if (lane == 0) sh[w] = v;
  __syncthreads();
  float r = 0.f;
  if (threadIdx.x == 0) {
    int nw = (blockDim.x + 63) >> 6;
    for (int i = 0; i < nw; ++i) r += sh[i];
  }
  return r;  // valid on thread 0 only
}

// exclusive scan over per-thread values, 1024-thread block
__device__ __forceinline__ int blockScanExclusive(int v, volatile int* wsums) {
  int lane = threadIdx.x & 63, w = threadIdx.x >> 6;
  int x = v;
#pragma unroll
  for (int o = 1; o < 64; o <<= 1) {
    int y = __shfl_up(x, o, 64);
    if (lane >= o) x += y;
  }
  if (lane == 63) wsums[w] = x;
  __syncthreads();
  if (threadIdx.x < 64) {
    int nw = blockDim.x >> 6;
    int s = (threadIdx.x < nw) ? wsums[threadIdx.x] : 0;
#pragma unroll
    for (int o = 1; o < 16; o <<= 1) {
      int y = __shfl_up(s, o, 64);
      if (lane >= o) s += y;
    }
    if (threadIdx.x < nw) wsums[threadIdx.x] = s;
  }
  __syncthreads();
  int base = (w > 0) ? wsums[w - 1] : 0;
  __syncthreads();
  return base + x - v;
}

// ---------------- graph build ----------------
__global__ void count_edges(const int* __restrict__ src, const int* __restrict__ dst,
                            int* __restrict__ co, int* __restrict__ ci, int E) {
  int e = blockIdx.x * blockDim.x + threadIdx.x;
  if (e >= E) return;
  atomicAdd(&co[src[e]], 1);
  atomicAdd(&ci[dst[e]], 1);
}

__global__ __launch_bounds__(1024) void exscan4096(const int* __restrict__ cnt,
                                                   int* __restrict__ ptr) {
  __shared__ int ls[1024];
  int t = threadIdx.x;
  int v0 = cnt[t * 4], v1 = cnt[t * 4 + 1], v2 = cnt[t * 4 + 2], v3 = cnt[t * 4 + 3];
  int s = v0 + v1 + v2 + v3;
  ls[t] = s;
  __syncthreads();
  for (int off = 1; off < 1024; off <<= 1) {
    int x = (t >= off) ? ls[t - off] : 0;
    __syncthreads();
    ls[t] += x;
    __syncthreads();
  }
  int ex = (t > 0) ? ls[t - 1] : 0;
  ptr[t * 4]     = ex;
  ptr[t * 4 + 1] = ex + v0;
  ptr[t * 4 + 2] = ex + v0 + v1;
  ptr[t * 4 + 3] = ex + v0 + v1 + v2;
  if (t == 1023) ptr[4096] = ex + s;
}

__global__ void fill_edges(const int* __restrict__ src, const int* __restrict__ dst,
                           const int* __restrict__ optr, const int* __restrict__ iptr,
                           int* __restrict__ fo, int* __restrict__ fi,
                           int* __restrict__ odst, int* __restrict__ isrc, int E) {
  int e = blockIdx.x * blockDim.x + threadIdx.x;
  if (e >= E) return;
  int s = src[e], d = dst[e];
  odst[optr[s] + atomicAdd(&fo[s], 1)] = d;
  isrc[iptr[d] + atomicAdd(&fi[d], 1)] = s;
}

__global__ void dinv0_kernel(const int* __restrict__ optr, float* __restrict__ dinv0) {
  int i = blockIdx.x * blockDim.x + threadIdx.x;
  if (i < N0) dinv0[i] = rsqrtf((float)(optr[i + 1] - optr[i]) + 1.0f);
}

// diag(A^2)[i], A = W + I, integer-exact 2-hop count. One wave/node.
__global__ __launch_bounds__(64) void diag2_kernel(const int* __restrict__ optr,
                                                   const int* __restrict__ odst,
                                                   float* __restrict__ diag2) {
  int i = blockIdx.x;
  int cnt = 0;
  int kbeg = optr[i], kend = optr[i + 1];
  for (int kk = kbeg - 1; kk < kend; ++kk) {
    int k = (kk < kbeg) ? i : odst[kk];
    int jbeg = optr[k], jend = optr[k + 1];
    for (int jj = jbeg - 1 + (int)threadIdx.x; jj < jend; jj += 64) {
      int j = (jj < jbeg) ? k : odst[jj];
      if (j == i) cnt++;
    }
  }
#pragma unroll
  for (int o = 32; o > 0; o >>= 1) cnt += __shfl_down(cnt, o, 64);
  if (threadIdx.x == 0) diag2[i] = (float)cnt;
}

// ---- dense matmul: C[M,N] = (A@B or A^T@B) * (dinv?dinv[row]:1) ----
template <bool TRANS_A>
__global__ void mm_kernel(const float* __restrict__ A, const float* __restrict__ B,
                          float* __restrict__ C, const float* __restrict__ dinv,
                          int M, int N, int K) {
  __shared__ float As[16][64];
  __shared__ float Bs[16][64];
  int tid = threadIdx.x;
  int nbx = N >> 6;
  int by = blockIdx.x / nbx, bx = blockIdx.x % nbx;
  int row0 = by << 6, col0 = bx << 6;
  int tx = tid & 15, ty = tid >> 4;
  float acc[4][4] = {{0.f}};
  for (int k0 = 0; k0 < K; k0 += 16) {
    if (TRANS_A) {
#pragma unroll
      for (int p = 0; p < 4; ++p) {
        int kk = (tid >> 6) + (p << 2);
        int i = tid & 63;
        As[kk][i] = A[(size_t)(k0 + kk) * M + row0 + i];
      }
    } else {
#pragma unroll
      for (int p = 0; p < 4; ++p) {
        int r = (tid >> 4) + (p << 4);
        int kk = tid & 15;
        As[kk][r] = A[(size_t)(row0 + r) * K + k0 + kk];
      }
    }
#pragma unroll
    for (int p = 0; p < 4; ++p) {
      int kk = (tid >> 6) + (p << 2);
      int c = tid & 63;
      Bs[kk][c] = B[(size_t)(k0 + kk) * N + col0 + c];
    }
    __syncthreads();
#pragma unroll
    for (int kk = 0; kk < 16; ++kk) {
      float a[4], b[4];
#pragma unroll
      for (int i = 0; i < 4; ++i) a[i] = As[kk][(ty << 2) + i];
#pragma unroll
      for (int j = 0; j < 4; ++j) b[j] = Bs[kk][(tx << 2) + j];
#pragma unroll
      for (int i = 0; i < 4; ++i)
#pragma unroll
        for (int j = 0; j < 4; ++j) acc[i][j] += a[i] * b[j];
    }
    __syncthreads();
  }
#pragma unroll
  for (int i = 0; i < 4; ++i) {
    int r = row0 + (ty << 2) + i;
    float dv = dinv ? dinv[r] : 1.f;
#pragma unroll
    for (int j = 0; j < 4; ++j) C[(size_t)r * N + col0 + (tx << 2) + j] = acc[i][j] * dv;
  }
}

// ---------------- W2 = A1[p2,:] @ A1[:,p2] via bf16 MFMA (integer-exact) ----------
__global__ __launch_bounds__(256) void mm_w2_mfma(const unsigned short* __restrict__ Wb,
                                                  const unsigned short* __restrict__ WbT,
                                                  const int* __restrict__ perm2,
                                                  float* __restrict__ W2) {
  __shared__ unsigned short As[64 * 64];
  __shared__ unsigned short Bs[64 * 64];
  __shared__ int pr[64], pc[64];
  int tid = threadIdx.x;
  int bx = blockIdx.x & 15, by = blockIdx.x >> 4;
  int row0 = by << 6, col0 = bx << 6;
  if (tid < 64) pr[tid] = perm2[row0 + tid];
  else if (tid < 128) pc[tid - 64] = perm2[col0 + tid - 128 + 64];
  __syncthreads();
  int l = tid & 63, wv = tid >> 6;
  int wr = (wv >> 1) << 5, wc = (wv & 1) << 5;
  f32x4 acc[2][2] = {};
  for (int k0 = 0; k0 < 2048; k0 += 64) {
#pragma unroll
    for (int it = 0; it < 2; ++it) {
      int idx = (it << 8) + tid;
      int r = idx >> 3, c8 = idx & 7;
      int sw = c8 ^ (r & 7);
      ((uint4*)As)[(r << 3) + sw] =
          *(const uint4*)(Wb + (size_t)pr[r] * 2048 + k0 + (c8 << 3));
      ((uint4*)Bs)[(r << 3) + sw] =
          *(const uint4*)(WbT + (size_t)pc[r] * 2048 + k0 + (c8 << 3));
    }
    __syncthreads();
    if (tid < 64) {
      int r = tid, d = pr[r] - k0;
      if (d >= 0 && d < 64) {
        int ui = (r << 6) + (((d >> 3) ^ (r & 7)) << 3) + (d & 7);
        As[ui] = f2bf(bf2f(As[ui]) + 1.f);
      }
    } else if (tid < 128) {
      int c = tid - 64, d = pc[c] - k0;
      if (d >= 0 && d < 64) {
        int ui = (c << 6) + (((d >> 3) ^ (c & 7)) << 3) + (d & 7);
        Bs[ui] = f2bf(bf2f(Bs[ui]) + 1.f);
      }
    }
    __syncthreads();
#pragma unroll
    for (int kk2 = 0; kk2 < 2; ++kk2) {
      int ch = (kk2 << 2) + (l >> 4);
      int ra = wr + (l & 15), rb = ra + 16;
      int ca = wc + (l & 15), cb = ca + 16;
      bf16x8 a0 = *(const bf16x8*)&As[(ra << 6) + ((ch ^ (ra & 7)) << 3)];
      bf16x8 a1 = *(const bf16x8*)&As[(rb << 6) + ((ch ^ (rb & 7)) << 3)];
      bf16x8 b0 = *(const bf16x8*)&Bs[(ca << 6) + ((ch ^ (ca & 7)) << 3)];
      bf16x8 b1 = *(const bf16x8*)&Bs[(cb << 6) + ((ch ^ (cb & 7)) << 3)];
      acc[0][0] = __builtin_amdgcn_mfma_f32_16x16x32_bf16(a0, b0, acc[0][0], 0, 0, 0);
      acc[0][1] = __builtin_amdgcn_mfma_f32_16x16x32_bf16(a0, b1, acc[0][1], 0, 0, 0);
      acc[1][0] = __builtin_amdgcn_mfma_f32_16x16x32_bf16(a1, b0, acc[1][0], 0, 0, 0);
      acc[1][1] = __builtin_amdgcn_mfma_f32_16x16x32_bf16(a1, b1, acc[1][1], 0, 0, 0);
    }
    __syncthreads();
  }
  int lrow = (l >> 4) << 2, lcol = l & 15;
#pragma unroll
  for (int i = 0; i < 2; ++i)
#pragma unroll
    for (int j = 0; j < 2; ++j)
#pragma unroll
      for (int rg = 0; rg < 4; ++rg) {
        int r = row0 + wr + (i << 4) + lrow + rg;
        int c = col0 + wc + (j << 4) + lcol;
        W2[(size_t)r * 1024 + c] = acc[i][j][rg];
      }
}

// 64x64-tile bf16 transpose
__global__ __launch_bounds__(256) void transpose_bf16(const unsigned short* __restrict__ in,
                                                      unsigned short* __restrict__ out,
                                                      int n) {
  __shared__ unsigned short t[64][65];
  int nb = n >> 6;
  int bx = blockIdx.x % nb, by = blockIdx.x / nb;
  int r0 = by << 6, c0 = bx << 6;
  for (int it = 0; it < 16; ++it) {
    int idx = (it << 8) + threadIdx.x;
    int r = idx >> 6, c = idx & 63;
    t[r][c] = in[(size_t)(r0 + r) * n + c0 + c];
  }
  __syncthreads();
  for (int it = 0; it < 16; ++it) {
    int idx = (it << 8) + threadIdx.x;
    int r = idx >> 6, c = idx & 63;
    out[(size_t)(c0 + r) * n + r0 + c] = t[c][r];
  }
}

// ---------------- elementwise / epilogues ----------------
__global__ void gcn_epi(const float* __restrict__ Y, const float* __restrict__ Z,
                        const float* __restrict__ dinv, const float* __restrict__ bias,
                        float* __restrict__ outp, int C, int total) {
  int idx = blockIdx.x * blockDim.x + threadIdx.x;
  if (idx >= total) return;
  int i = idx / C, c = idx % C;
  outp[idx] = fmaxf(dinv[i] * (Y[idx] + Z[idx]) + bias[c], 0.f);
}

// out[r,c] = relu(dinv[r]*(U2[p[r],c] + (1-diag2[p[r]])*Z[r,c]) + b[c])
__global__ void gcn_epi_sparse(const float* __restrict__ U2, const int* __restrict__ perm,
                               const float* __restrict__ diag2, const float* __restrict__ Z,
                               const float* __restrict__ dinv, const float* __restrict__ bias,
                               float* __restrict__ outp, int C, int total) {
  int idx = blockIdx.x * blockDim.x + threadIdx.x;
  if (idx >= total) return;
  int r = idx / C, c = idx % C;
  int p = perm[r];
  float v = U2[(size_t)p * C + c] + (1.f - diag2[p]) * Z[idx];
  outp[idx] = fmaxf(dinv[r] * v + bias[c], 0.f);
}

// first 2-hop pass with fused rank-gather: Zout[i,:]=g(i)+sum_in g(isrc), g(n)=rank[n]>=0?Zc[rank[n]]:0
template <int C>
__global__ __launch_bounds__(256) void atspmm_g(const int* __restrict__ iptr,
                                                const int* __restrict__ isrc,
                                                const int* __restrict__ rank,
                                                const float* __restrict__ Zc,
                                                float* __restrict__ Zout) {
  constexpr int L = C / 4;
  int li = threadIdx.x % L;
  int i = blockIdx.x * (256 / L) + threadIdx.x / L;
  float4 acc = make_float4(0.f, 0.f, 0.f, 0.f);
  int r0 = rank[i];
  if (r0 >= 0) acc = *(const float4*)(Zc + (size_t)r0 * C + li * 4);
  int beg = iptr[i], end = iptr[i + 1];
  for (int e = beg; e < end; ++e) {
    int rs = rank[isrc[e]];
    if (rs >= 0) {
      float4 z = *(const float4*)(Zc + (size_t)rs * C + li * 4);
      acc.x += z.x; acc.y += z.y; acc.z += z.z; acc.w += z.w;
    }
  }
  *(float4*)(Zout + (size_t)i * C + li * 4) = acc;
}

// second 2-hop pass (full): Zout[i,:] = Zin[i,:] + sum_in Zin[isrc[e],:]
template <int C>
__global__ __launch_bounds__(256) void atspmm4(const int* __restrict__ iptr,
                                               const int* __restrict__ isrc,
                                               const float* __restrict__ Zin,
                                               float* __restrict__ Zout) {
  constexpr int L = C / 4;
  int li = threadIdx.x % L;
  int i = blockIdx.x * (256 / L) + threadIdx.x / L;
  float4 acc = *(const float4*)(Zin + (size_t)i * C + li * 4);
  int beg = iptr[i], end = iptr[i + 1];
  for (int e = beg; e < end; ++e) {
    float4 z = *(const float4*)(Zin + (size_t)isrc[e] * C + li * 4);
    acc.x += z.x; acc.y += z.y; acc.z += z.z; acc.w += z.w;
  }
  *(float4*)(Zout + (size_t)i * C + li * 4) = acc;
}

// level-0 GCN: out[i,:] = relu(dinv[i]*(Z[i,:] + sum_in Z[isrc,:]) + b)
template <int C>
__global__ __launch_bounds__(256) void gcn_spmm4(const int* __restrict__ iptr,
                                                 const int* __restrict__ isrc,
                                                 const float* __restrict__ Z,
                                                 const float* __restrict__ dinv,
                                                 const float* __restrict__ bias,
                                                 float* __restrict__ outp) {
  constexpr int L = C / 4;
  int li = threadIdx.x % L;
  int i = blockIdx.x * (256 / L) + threadIdx.x / L;
  float4 acc = *(const float4*)(Z + (size_t)i * C + li * 4);
  int beg = iptr[i], end = iptr[i + 1];
  for (int e = beg; e < end; ++e) {
    float4 z = *(const float4*)(Z + (size_t)isrc[e] * C + li * 4);
    acc.x += z.x; acc.y += z.y; acc.z += z.z; acc.w += z.w;
  }
  float d = dinv[i];
  float4 bb = *(const float4*)(bias + li * 4);
  float4 o;
  o.x = fmaxf(d * acc.x + bb.x, 0.f);
  o.y = fmaxf(d * acc.y + bb.y, 0.f);
  o.z = fmaxf(d * acc.z + bb.z, 0.f);
  o.w = fmaxf(d * acc.w + bb.w, 0.f);
  *(float4*)(outp + (size_t)i * C + li * 4) = o;
}

__global__ void gather_scale(const float* __restrict__ X, const int* __restrict__ perm,
                             const float* __restrict__ vals, float* __restrict__ outp,
                             int C, int total) {
  int idx = blockIdx.x * blockDim.x + threadIdx.x;
  if (idx >= total) return;
  int a = idx / C, c = idx % C;
  outp[idx] = X[(size_t)perm[a] * C + c] * vals[a];
}

// out = base + scatter(up) via rank (in-place safe)
__global__ void add_up(const float* base, const int* __restrict__ rank,
                       const float* __restrict__ up, float* outp, int C, int total) {
  int idx = blockIdx.x * blockDim.x + threadIdx.x;
  if (idx >= total) return;
  int r = idx / C, c = idx % C;
  int rk = rank[r];
  float v = base[idx];
  if (rk >= 0) v += up[(size_t)rk * C + c];
  outp[idx] = v;
}

__global__ void score_kernel(const float* __restrict__ X, int C,
                             const float* __restrict__ p, float* __restrict__ sc) {
  int i = blockIdx.x;
  float s1 = 0.f, s2 = 0.f;
  for (int c = threadIdx.x; c < C; c += blockDim.x) {
    float pv = p[c];
    s1 += pv * pv;
    s2 += X[(size_t)i * C + c] * pv;
  }
  float r1 = blockReduceSum256(s1);
  __syncthreads();
  float r2 = blockReduceSum256(s2);
  if (threadIdx.x == 0) sc[i] = tanhf(r2 / sqrtf(r1));
}

// ---- top-k via radix select (exact value threshold + index-ordered ties) ----
__global__ __launch_bounds__(1024) void topk_select(const float* __restrict__ score,
                                                    int n, int k, int* __restrict__ perm,
                                                    float* __restrict__ vals,
                                                    int* __restrict__ rank) {
  __shared__ unsigned int keys[4096];
  __shared__ int hist[256];
  __shared__ int wsums[16];
  __shared__ unsigned int sh_prefix;
  __shared__ int sh_rem;
  int t = threadIdx.x;
  int m = n >> 10;  // elements per thread (4 or 2)
  for (int i = t; i < n; i += 1024) {
    unsigned int u = __float_as_uint(score[i]);
    keys[i] = u ^ ((unsigned int)((int)u >> 31) | 0x80000000u);  // order-preserving
  }
  if (t == 0) { sh_prefix = 0u; sh_rem = k; }
  __syncthreads();
  for (int round = 0; round < 4; ++round) {
    int shift = 24 - (round << 3);
    if (t < 256) hist[t] = 0;
    __syncthreads();
    unsigned int prefix = sh_prefix;
    unsigned int maskhi = (round == 0) ? 0u : (0xFFFFFFFFu << (shift + 8));
    for (int i = t; i < n; i += 1024) {
      unsigned int kk = keys[i];
      if ((kk & maskhi) == prefix) atomicAdd(&hist[(kk >> shift) & 255], 1);
    }
    __syncthreads();
    if (t == 0) {
      int rem = sh_rem, acc = 0, b = 255;
      for (; b > 0; --b) {
        if (acc + hist[b] >= rem) break;
        acc += hist[b];
      }
      sh_rem = rem - acc;
      sh_prefix = prefix | ((unsigned int)b << shift);
    }
    __syncthreads();
  }
  unsigned int thr = sh_prefix;
  int need = sh_rem;
  int base = t * m;
  int f[4];
  int cnt = 0;
#pragma unroll
  for (int j = 0; j < 4; ++j) {
    f[j] = 0;
    if (j < m) { f[j] = (keys[base + j] == thr) ? 1 : 0; cnt += f[j]; }
  }
  int ex = blockScanExclusive(cnt, wsums);
  int sel[4];
  int scnt = 0;
#pragma unroll
  for (int j = 0; j < 4; ++j) {
    sel[j] = 0;
    if (j < m) {
      unsigned int kk = keys[base + j];
      sel[j] = (kk > thr) || (kk == thr && ex < need);
      ex += f[j];
      scnt += sel[j];
    }
  }
  int pos = blockScanExclusive(scnt, wsums);
#pragma unroll
  for (int j = 0; j < 4; ++j) {
    if (j < m) {
      int i = base + j;
      if (sel[j]) {
        unsigned int kk = keys[i];
        unsigned int u = (kk & 0x80000000u) ? (kk ^ 0x80000000u) : ~kk;
        perm[pos] = i;
        vals[pos] = __uint_as_float(u);
        rank[i] = pos;
        pos++;
      } else {
        rank[i] = -1;
      }
    }
  }
}

// W1[a,b] (bf16, integer-exact) + dinv1
__global__ void build_W1(const int* __restrict__ optr, const int* __restrict__ odst,
                         const int* __restrict__ perm1, const int* __restrict__ rank1,
                         unsigned short* __restrict__ W1b, float* __restrict__ dinv1) {
  __shared__ float row[2048];
  int a = blockIdx.x;
  int pa = perm1[a];
  for (int i = threadIdx.x; i < 2048; i += blockDim.x) row[i] = 0.f;
  __syncthreads();
  int kbeg = optr[pa], kend = optr[pa + 1];
  for (int kk = kbeg - 1; kk < kend; ++kk) {
    int k = (kk < kbeg) ? pa : odst[kk];
    int jbeg = optr[k], jend = optr[k + 1];
    for (int jj = jbeg - 1 + (int)threadIdx.x; jj < jend; jj += (int)blockDim.x) {
      int j = (jj < jbeg) ? k : odst[jj];
      int rb = rank1[j];
      if (rb >= 0) atomicAdd(&row[rb], 1.0f);
    }
  }
  __syncthreads();
  float ssum = 0.f;
  for (int i = threadIdx.x; i < 2048; i += blockDim.x) {
    float v = (i == a) ? 0.f : row[i];
    W1b[(size_t)a * 2048 + i] = f2bf(v);
    ssum += v;
  }
  float t = blockReduceSum256(ssum);
  if (threadIdx.x == 0) dinv1[a] = rsqrtf(t + 1.0f);
}

__global__ void postW2(float* __restrict__ W2, float* __restrict__ dinv2) {
  int a = blockIdx.x;
  float ssum = 0.f;
  for (int i = threadIdx.x; i < 1024; i += blockDim.x) {
    float v = W2[(size_t)a * 1024 + i];
    if (i == a) { W2[(size_t)a * 1024 + i] = 0.f; v = 0.f; }
    ssum += v;
  }
  float t = blockReduceSum256(ssum);
  if (threadIdx.x == 0) dinv2[a] = rsqrtf(t + 1.0f);
}

__global__ void mean_cols(const float* __restrict__ X, int R, int C, float* __restrict__ outp) {
  int c = blockIdx.x;
  float s = 0.f;
  for (int r = threadIdx.x; r < R; r += blockDim.x) s += X[(size_t)r * C + c];
  float t = blockReduceSum256(s);
  if (threadIdx.x == 0) outp[c] = t / (float)R;
}

// ---------------- launcher ----------------
extern "C" void kernel_launch(void* const* d_in, const int* in_sizes, int n_in,
                              void* d_out, int out_size, void* d_ws, size_t ws_size,
                              hipStream_t stream) {
  const float* x      = (const float*)d_in[0];
  const int*   eidx   = (const int*)d_in[1];
  const float* theta0 = (const float*)d_in[2];
  const float* b0     = (const float*)d_in[3];
  const float* theta1 = (const float*)d_in[4];
  const float* b1     = (const float*)d_in[5];
  const float* theta2 = (const float*)d_in[6];
  const float* b2     = (const float*)d_in[7];
  const float* theta3 = (const float*)d_in[8];
  const float* b3     = (const float*)d_in[9];
  const float* theta4 = (const float*)d_in[10];
  const float* b4     = (const float*)d_in[11];
  const float* p1     = (const float*)d_in[12];
  const float* p2     = (const float*)d_in[13];
  const int E = in_sizes[1] / 2;
  const int* src = eidx;
  const int* dst = eidx + E;
  float* out = (float*)d_out;

  char* wsb = (char*)d_ws;
  size_t off = 0;
  auto alloc = [&](size_t bytes) -> void* {
    void* p = wsb + off;
    off = (off + bytes + 255) & ~(size_t)255;
    return p;
  };
  int* optr  = (int*)alloc((N0 + 1) * 4);
  int* iptr  = (int*)alloc((N0 + 1) * 4);
  int* odst  = (int*)alloc((size_t)E * 4);
  int* isrc  = (int*)alloc((size_t)E * 4);
  int* cnt4  = (int*)alloc((size_t)4 * N0 * 4);
  int* perm1 = (int*)alloc(P1K * 4);
  int* rank1 = (int*)alloc(N0 * 4);
  int* perm2 = (int*)alloc(P2K * 4);
  int* rank2 = (int*)alloc(P1K * 4);
  float* dinv0 = (float*)alloc(N0 * 4);
  float* dinv1 = (float*)alloc(P1K * 4);
  float* dinv2 = (float*)alloc(P2K * 4);
  float* vals1 = (float*)alloc(P1K * 4);
  float* vals2 = (float*)alloc(P2K * 4);
  float* score = (float*)alloc(N0 * 4);
  float* diag2 = (float*)alloc(N0 * 4);
  float* x0  = (float*)alloc((size_t)N0 * 256 * 4);
  float* x1  = (float*)alloc((size_t)P1K * 256 * 4);
  float* x1b = (float*)alloc((size_t)P1K * 512 * 4);
  float* x2  = (float*)alloc((size_t)P2K * 512 * 4);
  float* xb  = (float*)alloc((size_t)P2K * 512 * 4);
  float* xu  = (float*)alloc((size_t)P1K * 256 * 4);
  float* SA  = (float*)alloc((size_t)P1K * 512 * 4);       // Z scratch
  float* SC  = (float*)alloc((size_t)P2K * 512 * 4);       // gcn2 Y scratch
  float* ZF  = (float*)alloc((size_t)N0 * 512 * 4);        // U2
  float* ZU  = (float*)alloc((size_t)N0 * 512 * 4);        // U1
  unsigned short* W1b  = (unsigned short*)alloc((size_t)P1K * P1K * 2);
  unsigned short* W1bT = (unsigned short*)alloc((size_t)P1K * P1K * 2);
  float* W2  = (float*)alloc((size_t)P2K * P2K * 4);
  (void)ws_size; (void)n_in; (void)out_size;

  int* co = cnt4;
  int* ci = cnt4 + N0;
  int* fo = cnt4 + 2 * N0;
  int* fi = cnt4 + 3 * N0;

  // --- graph build ---
  hipMemsetAsync(cnt4, 0, (size_t)4 * N0 * 4, stream);
  count_edges<<<E / 256, 256, 0, stream>>>(src, dst, co, ci, E);
  exscan4096<<<1, 1024, 0, stream>>>(co, optr);
  exscan4096<<<1, 1024, 0, stream>>>(ci, iptr);
  fill_edges<<<E / 256, 256, 0, stream>>>(src, dst, optr, iptr, fo, fi, odst, isrc, E);
  dinv0_kernel<<<N0 / 256, 256, 0, stream>>>(optr, dinv0);
  diag2_kernel<<<N0, 64, 0, stream>>>(optr, odst, diag2);

  // --- gcn0: x[4096,128] -> x0[4096,256] ---
  mm_kernel<false><<<(4096 / 64) * (256 / 64), 256, 0, stream>>>(x, theta0, SA, dinv0,
                                                                 4096, 256, 128);
  gcn_spmm4<256><<<1024, 256, 0, stream>>>(iptr, isrc, SA, dinv0, b0, x0);

  // --- pool 1 ---
  score_kernel<<<4096, 256, 0, stream>>>(x0, 256, p1, score);
  topk_select<<<1, 1024, 0, stream>>>(score, 4096, 2048, perm1, vals1, rank1);
  gather_scale<<<2048 * 256 / 256, 256, 0, stream>>>(x0, perm1, vals1, x1, 256, 2048 * 256);
  build_W1<<<2048, 256, 0, stream>>>(optr, odst, perm1, rank1, W1b, dinv1);
  transpose_bf16<<<(2048 / 64) * (2048 / 64), 256, 0, stream>>>(W1b, W1bT, 2048);

  // --- gcn1 (sparse 2-hop agg): x1[2048,256] -> x1b[2048,512] ---
  mm_kernel<false><<<(2048 / 64) * (512 / 64), 256, 0, stream>>>(x1, theta1, SA, dinv1,
                                                                 2048, 512, 256);
  atspmm_g<512><<<2048, 256, 0, stream>>>(iptr, isrc, rank1, SA, ZU);
  atspmm4<512><<<2048, 256, 0, stream>>>(iptr, isrc, ZU, ZF);
  gcn_epi_sparse<<<2048 * 512 / 256, 256, 0, stream>>>(ZF, perm1, diag2, SA, dinv1, b1,
                                                       x1b, 512, 2048 * 512);

  // --- pool 2 ---
  score_kernel<<<2048, 256, 0, stream>>>(x1b, 512, p2, score);
  topk_select<<<1, 1024, 0, stream>>>(score, 2048, 1024, perm2, vals2, rank2);
  gather_scale<<<1024 * 512 / 256, 256, 0, stream>>>(x1b, perm2, vals2, x2, 512, 1024 * 512);
  mm_w2_mfma<<<16 * 16, 256, 0, stream>>>(W1b, W1bT, perm2, W2);
  postW2<<<1024, 256, 0, stream>>>(W2, dinv2);

  // --- gcn2 (bottleneck): x2[1024,512] -> xb[1024,512] ---
  mm_kernel<false><<<(1024 / 64) * (512 / 64), 256, 0, stream>>>(x2, theta2, SA, dinv2,
                                                                 1024, 512, 512);
  mm_kernel<true><<<(1024 / 64) * (512 / 64), 256, 0, stream>>>(W2, SA, SC, nullptr,
                                                                1024, 512, 1024);
  gcn_epi<<<1024 * 512 / 256, 256, 0, stream>>>(SC, SA, dinv2, b2, xb, 512, 1024 * 512);
  mean_cols<<<512, 256, 0, stream>>>(xb, 1024, 512, out + 524288);

  // --- up block 1 (sparse 2-hop agg): -> xu[2048,256] ---
  add_up<<<2048 * 512 / 256, 256, 0, stream>>>(x1b, rank2, xb, x1b, 512, 2048 * 512);
  mm_kernel<false><<<(2048 / 64) * (256 / 64), 256, 0, stream>>>(x1b, theta3, SA, dinv1,
                                                                 2048, 256, 512);
  atspmm_g<256><<<1024, 256, 0, stream>>>(iptr, isrc, rank1, SA, ZU);
  atspmm4<256><<<1024, 256, 0, stream>>>(iptr, isrc, ZU, ZF);
  gcn_epi_sparse<<<2048 * 256 / 256, 256, 0, stream>>>(ZF, perm1, diag2, SA, dinv1, b3,
                                                       xu, 256, 2048 * 256);

  // --- up block 0: -> out[4096,128] ---
  add_up<<<4096 * 256 / 256, 256, 0, stream>>>(x0, rank1, xu, x0, 256, 4096 * 256);
  mm_kernel<false><<<(4096 / 64) * (128 / 64), 256, 0, stream>>>(x0, theta4, SA, dinv0,
                                                                 4096, 128, 256);
  gcn_spmm4<128><<<512, 256, 0, stream>>>(iptr, isrc, SA, dinv0, b4, out);
}

// Round 4
// 472.591 us; speedup vs baseline: 1.8525x; 1.2082x over previous
//
#include <hip/hip_runtime.h>

#define N0 4096
#define P1K 2048
#define P2K 1024

typedef short bf16x8 __attribute__((ext_vector_type(8)));
typedef float f32x4 __attribute__((ext_vector_type(4)));
typedef unsigned short us4 __attribute__((ext_vector_type(4)));

__device__ __forceinline__ unsigned short f2bf(float f) {
  unsigned int u = __float_as_uint(f);
  unsigned int r = (u + 0x7fff + ((u >> 16) & 1)) >> 16;
  return (unsigned short)r;
}
__device__ __forceinline__ float bf2f(unsigned short h) {
  unsigned int u = ((unsigned int)h) << 16;
  return __uint_as_float(u);
}

// ---------------- helpers ----------------
__device__ __forceinline__ float blockReduceSum256(float v) {
  __shared__ float sh[16];
  int lane = threadIdx.x & 63;
  int w = threadIdx.x >> 6;
#pragma unroll
  for (int o = 32; o > 0; o >>= 1) v += __shfl_down(v, o, 64);
  __syncthreads();
  if (lane == 0) sh[w] = v;
  __syncthreads();
  float r = 0.f;
  if (threadIdx.x == 0) {
    int nw = (blockDim.x + 63) >> 6;
    for (int i = 0; i < nw; ++i) r += sh[i];
  }
  return r;  // valid on thread 0 only
}

__device__ __forceinline__ int blockScanExclusive(int v, volatile int* wsums) {
  int lane = threadIdx.x & 63, w = threadIdx.x >> 6;
  int x = v;
#pragma unroll
  for (int o = 1; o < 64; o <<= 1) {
    int y = __shfl_up(x, o, 64);
    if (lane >= o) x += y;
  }
  if (lane == 63) wsums[w] = x;
  __syncthreads();
  if (threadIdx.x < 64) {
    int nw = blockDim.x >> 6;
    int s = (threadIdx.x < nw) ? wsums[threadIdx.x] : 0;
#pragma unroll
    for (int o = 1; o < 16; o <<= 1) {
      int y = __shfl_up(s, o, 64);
      if (lane >= o) s += y;
    }
    if (threadIdx.x < nw) wsums[threadIdx.x] = s;
  }
  __syncthreads();
  int base = (w > 0) ? wsums[w - 1] : 0;
  __syncthreads();
  return base + x - v;
}

// ---------------- graph build ----------------
__global__ void count_edges(const int* __restrict__ src, const int* __restrict__ dst,
                            int* __restrict__ co, int* __restrict__ ci, int E) {
  int e = blockIdx.x * blockDim.x + threadIdx.x;
  if (e >= E) return;
  atomicAdd(&co[src[e]], 1);
  atomicAdd(&ci[dst[e]], 1);
}

__global__ __launch_bounds__(1024) void exscan4096(const int* __restrict__ cnt,
                                                   int* __restrict__ ptr) {
  __shared__ int ls[1024];
  int t = threadIdx.x;
  int v0 = cnt[t * 4], v1 = cnt[t * 4 + 1], v2 = cnt[t * 4 + 2], v3 = cnt[t * 4 + 3];
  int s = v0 + v1 + v2 + v3;
  ls[t] = s;
  __syncthreads();
  for (int off = 1; off < 1024; off <<= 1) {
    int x = (t >= off) ? ls[t - off] : 0;
    __syncthreads();
    ls[t] += x;
    __syncthreads();
  }
  int ex = (t > 0) ? ls[t - 1] : 0;
  ptr[t * 4]     = ex;
  ptr[t * 4 + 1] = ex + v0;
  ptr[t * 4 + 2] = ex + v0 + v1;
  ptr[t * 4 + 3] = ex + v0 + v1 + v2;
  if (t == 1023) ptr[4096] = ex + s;
}

__global__ void fill_edges(const int* __restrict__ src, const int* __restrict__ dst,
                           const int* __restrict__ optr, const int* __restrict__ iptr,
                           int* __restrict__ fo, int* __restrict__ fi,
                           int* __restrict__ odst, int* __restrict__ isrc, int E) {
  int e = blockIdx.x * blockDim.x + threadIdx.x;
  if (e >= E) return;
  int s = src[e], d = dst[e];
  odst[optr[s] + atomicAdd(&fo[s], 1)] = d;
  isrc[iptr[d] + atomicAdd(&fi[d], 1)] = s;
}

__global__ void dinv0_kernel(const int* __restrict__ optr, float* __restrict__ dinv0) {
  int i = blockIdx.x * blockDim.x + threadIdx.x;
  if (i < N0) dinv0[i] = rsqrtf((float)(optr[i + 1] - optr[i]) + 1.0f);
}

__global__ __launch_bounds__(64) void diag2_kernel(const int* __restrict__ optr,
                                                   const int* __restrict__ odst,
                                                   float* __restrict__ diag2) {
  int i = blockIdx.x;
  int cnt = 0;
  int kbeg = optr[i], kend = optr[i + 1];
  for (int kk = kbeg - 1; kk < kend; ++kk) {
    int k = (kk < kbeg) ? i : odst[kk];
    int jbeg = optr[k], jend = optr[k + 1];
    for (int jj = jbeg - 1 + (int)threadIdx.x; jj < jend; jj += 64) {
      int j = (jj < jbeg) ? k : odst[jj];
      if (j == i) cnt++;
    }
  }
#pragma unroll
  for (int o = 32; o > 0; o >>= 1) cnt += __shfl_down(cnt, o, 64);
  if (threadIdx.x == 0) diag2[i] = (float)cnt;
}

// ---- fp32 score-critical GEMM: 32x64 tile, 512-block grids for occupancy ----
__global__ __launch_bounds__(256) void mm32(const float* __restrict__ A,
                                            const float* __restrict__ B,
                                            float* __restrict__ C,
                                            const float* __restrict__ dinv,
                                            int M, int N, int K) {
  __shared__ float As[16][32];
  __shared__ float Bs[16][64];
  int tid = threadIdx.x;
  int nbx = N >> 6;
  int by = blockIdx.x / nbx, bx = blockIdx.x % nbx;
  int row0 = by << 5, col0 = bx << 6;
  int tx = tid & 15, ty = tid >> 4;
  float acc[2][4] = {{0.f}};
  for (int k0 = 0; k0 < K; k0 += 16) {
    {
      int r = tid >> 3;
      int kk = (tid & 7) << 1;
      float2 v = *(const float2*)(A + (size_t)(row0 + r) * K + k0 + kk);
      As[kk][r] = v.x;
      As[kk + 1][r] = v.y;
    }
#pragma unroll
    for (int p = 0; p < 4; ++p) {
      int kk = (tid >> 6) + (p << 2);
      int c = tid & 63;
      Bs[kk][c] = B[(size_t)(k0 + kk) * N + col0 + c];
    }
    __syncthreads();
#pragma unroll
    for (int kk = 0; kk < 16; ++kk) {
      float a0 = As[kk][ty << 1], a1 = As[kk][(ty << 1) + 1];
      float4 b = *(const float4*)&Bs[kk][tx << 2];
      acc[0][0] += a0 * b.x; acc[0][1] += a0 * b.y;
      acc[0][2] += a0 * b.z; acc[0][3] += a0 * b.w;
      acc[1][0] += a1 * b.x; acc[1][1] += a1 * b.y;
      acc[1][2] += a1 * b.z; acc[1][3] += a1 * b.w;
    }
    __syncthreads();
  }
#pragma unroll
  for (int i = 0; i < 2; ++i) {
    int r = row0 + (ty << 1) + i;
    float dv = dinv ? dinv[r] : 1.f;
#pragma unroll
    for (int j = 0; j < 4; ++j) C[(size_t)r * N + col0 + (tx << 2) + j] = acc[i][j] * dv;
  }
}

// ---- generic bf16 MFMA GEMM: C[M,N] = A@B, B given transposed bf16 (BT[N][K]) ----
// ABF16: A already bf16 [M][K]; else fp32 (converted in staging).
// EPI=0: Cf = acc*dinv[r] (dinv opt), optional CbT[N][M] bf16 (transposed dual-write)
// EPI=1: Cf = relu(dinv[r]*(acc + Zadd[r,c]) + bias[c])
template <bool ABF16, int EPI>
__global__ __launch_bounds__(256) void gemm_ab(const void* __restrict__ Av,
                                               const unsigned short* __restrict__ BT,
                                               const float* __restrict__ Zadd,
                                               const float* __restrict__ dinv,
                                               const float* __restrict__ bias,
                                               float* __restrict__ Cf,
                                               unsigned short* __restrict__ CbT,
                                               int M, int N, int K) {
  __shared__ unsigned short As[64 * 64];
  __shared__ unsigned short Bs[64 * 64];
  int tid = threadIdx.x;
  int nbx = N >> 6;
  int by = blockIdx.x / nbx, bx = blockIdx.x % nbx;
  int row0 = by << 6, col0 = bx << 6;
  int l = tid & 63, wv = tid >> 6;
  int wr = (wv >> 1) << 5, wc = (wv & 1) << 5;
  f32x4 acc[2][2] = {};
  for (int k0 = 0; k0 < K; k0 += 64) {
#pragma unroll
    for (int it = 0; it < 2; ++it) {
      int idx = (it << 8) + tid;
      int r = idx >> 3, c8 = idx & 7;
      int sw = c8 ^ (r & 7);
      if (ABF16) {
        ((uint4*)As)[(r << 3) + sw] =
            *(const uint4*)((const unsigned short*)Av + (size_t)(row0 + r) * K + k0 + (c8 << 3));
      } else {
        const float* Af = (const float*)Av + (size_t)(row0 + r) * K + k0 + (c8 << 3);
        float4 f0 = *(const float4*)Af;
        float4 f1 = *(const float4*)(Af + 4);
        uint4 u;
        u.x = (unsigned)f2bf(f0.x) | ((unsigned)f2bf(f0.y) << 16);
        u.y = (unsigned)f2bf(f0.z) | ((unsigned)f2bf(f0.w) << 16);
        u.z = (unsigned)f2bf(f1.x) | ((unsigned)f2bf(f1.y) << 16);
        u.w = (unsigned)f2bf(f1.z) | ((unsigned)f2bf(f1.w) << 16);
        ((uint4*)As)[(r << 3) + sw] = u;
      }
      ((uint4*)Bs)[(r << 3) + sw] =
          *(const uint4*)(BT + (size_t)(col0 + r) * K + k0 + (c8 << 3));
    }
    __syncthreads();
#pragma unroll
    for (int kk2 = 0; kk2 < 2; ++kk2) {
      int ch = (kk2 << 2) + (l >> 4);
      int ra = wr + (l & 15), rb = ra + 16;
      int ca = wc + (l & 15), cb = ca + 16;
      bf16x8 a0 = *(const bf16x8*)&As[(ra << 6) + ((ch ^ (ra & 7)) << 3)];
      bf16x8 a1 = *(const bf16x8*)&As[(rb << 6) + ((ch ^ (rb & 7)) << 3)];
      bf16x8 b0 = *(const bf16x8*)&Bs[(ca << 6) + ((ch ^ (ca & 7)) << 3)];
      bf16x8 b1 = *(const bf16x8*)&Bs[(cb << 6) + ((ch ^ (cb & 7)) << 3)];
      acc[0][0] = __builtin_amdgcn_mfma_f32_16x16x32_bf16(a0, b0, acc[0][0], 0, 0, 0);
      acc[0][1] = __builtin_amdgcn_mfma_f32_16x16x32_bf16(a0, b1, acc[0][1], 0, 0, 0);
      acc[1][0] = __builtin_amdgcn_mfma_f32_16x16x32_bf16(a1, b0, acc[1][0], 0, 0, 0);
      acc[1][1] = __builtin_amdgcn_mfma_f32_16x16x32_bf16(a1, b1, acc[1][1], 0, 0, 0);
    }
    __syncthreads();
  }
  int lrow = (l >> 4) << 2, lcol = l & 15;
#pragma unroll
  for (int i = 0; i < 2; ++i) {
#pragma unroll
    for (int j = 0; j < 2; ++j) {
      int c = col0 + wc + (j << 4) + lcol;
      int r0 = row0 + wr + (i << 4) + lrow;
      if (EPI == 0) {
#pragma unroll
        for (int rg = 0; rg < 4; ++rg) {
          int r = r0 + rg;
          float dv = dinv ? dinv[r] : 1.f;
          Cf[(size_t)r * N + c] = acc[i][j][rg] * dv;
        }
        if (CbT) {
          us4 pk;
#pragma unroll
          for (int rg = 0; rg < 4; ++rg) {
            float dv = dinv ? dinv[r0 + rg] : 1.f;
            pk[rg] = f2bf(acc[i][j][rg] * dv);
          }
          *(us4*)(CbT + (size_t)c * M + r0) = pk;
        }
      } else {
#pragma unroll
        for (int rg = 0; rg < 4; ++rg) {
          int r = r0 + rg;
          float v = dinv[r] * (acc[i][j][rg] + Zadd[(size_t)r * N + c]) + bias[c];
          Cf[(size_t)r * N + c] = fmaxf(v, 0.f);
        }
      }
    }
  }
}

// ---- W2T(bf16) = (A1[p2,:]@A1[:,p2])^T with diag-zero + fused row sums -----
__global__ __launch_bounds__(256) void mm_w2_mfma(const unsigned short* __restrict__ Wb,
                                                  const unsigned short* __restrict__ WbT,
                                                  const int* __restrict__ perm2,
                                                  unsigned short* __restrict__ W2Tb,
                                                  float* __restrict__ degsum2) {
  __shared__ unsigned short As[64 * 64];
  __shared__ unsigned short Bs[64 * 64];
  __shared__ int pr[64], pc[64];
  int tid = threadIdx.x;
  int bx = blockIdx.x & 15, by = blockIdx.x >> 4;
  int row0 = by << 6, col0 = bx << 6;
  if (tid < 64) pr[tid] = perm2[row0 + tid];
  else if (tid < 128) pc[tid - 64] = perm2[col0 + tid - 128 + 64];
  __syncthreads();
  int l = tid & 63, wv = tid >> 6;
  int wr = (wv >> 1) << 5, wc = (wv & 1) << 5;
  f32x4 acc[2][2] = {};
  for (int k0 = 0; k0 < 2048; k0 += 64) {
#pragma unroll
    for (int it = 0; it < 2; ++it) {
      int idx = (it << 8) + tid;
      int r = idx >> 3, c8 = idx & 7;
      int sw = c8 ^ (r & 7);
      ((uint4*)As)[(r << 3) + sw] =
          *(const uint4*)(Wb + (size_t)pr[r] * 2048 + k0 + (c8 << 3));
      ((uint4*)Bs)[(r << 3) + sw] =
          *(const uint4*)(WbT + (size_t)pc[r] * 2048 + k0 + (c8 << 3));
    }
    __syncthreads();
    if (tid < 64) {
      int r = tid, d = pr[r] - k0;
      if (d >= 0 && d < 64) {
        int ui = (r << 6) + (((d >> 3) ^ (r & 7)) << 3) + (d & 7);
        As[ui] = f2bf(bf2f(As[ui]) + 1.f);
      }
    } else if (tid < 128) {
      int c = tid - 64, d = pc[c] - k0;
      if (d >= 0 && d < 64) {
        int ui = (c << 6) + (((d >> 3) ^ (c & 7)) << 3) + (d & 7);
        Bs[ui] = f2bf(bf2f(Bs[ui]) + 1.f);
      }
    }
    __syncthreads();
#pragma unroll
    for (int kk2 = 0; kk2 < 2; ++kk2) {
      int ch = (kk2 << 2) + (l >> 4);
      int ra = wr + (l & 15), rb = ra + 16;
      int ca = wc + (l & 15), cb = ca + 16;
      bf16x8 a0 = *(const bf16x8*)&As[(ra << 6) + ((ch ^ (ra & 7)) << 3)];
      bf16x8 a1 = *(const bf16x8*)&As[(rb << 6) + ((ch ^ (rb & 7)) << 3)];
      bf16x8 b0 = *(const bf16x8*)&Bs[(ca << 6) + ((ch ^ (ca & 7)) << 3)];
      bf16x8 b1 = *(const bf16x8*)&Bs[(cb << 6) + ((ch ^ (cb & 7)) << 3)];
      acc[0][0] = __builtin_amdgcn_mfma_f32_16x16x32_bf16(a0, b0, acc[0][0], 0, 0, 0);
      acc[0][1] = __builtin_amdgcn_mfma_f32_16x16x32_bf16(a0, b1, acc[0][1], 0, 0, 0);
      acc[1][0] = __builtin_amdgcn_mfma_f32_16x16x32_bf16(a1, b0, acc[1][0], 0, 0, 0);
      acc[1][1] = __builtin_amdgcn_mfma_f32_16x16x32_bf16(a1, b1, acc[1][1], 0, 0, 0);
    }
    __syncthreads();
  }
  int lrow = (l >> 4) << 2, lcol = l & 15;
#pragma unroll
  for (int i = 0; i < 2; ++i) {
#pragma unroll
    for (int rg = 0; rg < 4; ++rg) {
      int r = row0 + wr + (i << 4) + lrow + rg;
      float rs = 0.f;
#pragma unroll
      for (int j = 0; j < 2; ++j) {
        int c = col0 + wc + (j << 4) + lcol;
        float v = acc[i][j][rg];
        if (r == c) v = 0.f;
        W2Tb[(size_t)c * 1024 + r] = f2bf(v);
        rs += v;
      }
#pragma unroll
      for (int o = 1; o < 16; o <<= 1) rs += __shfl_xor(rs, o, 64);
      if ((l & 15) == 0) atomicAdd(&degsum2[r], rs);  // integer values: exact, order-free
    }
  }
}

__global__ void dinv2_kernel(const float* __restrict__ degsum2, float* __restrict__ dinv2) {
  int i = blockIdx.x * blockDim.x + threadIdx.x;
  if (i < P2K) dinv2[i] = rsqrtf(degsum2[i] + 1.0f);
}

// 64x64-tile bf16 transpose
__global__ __launch_bounds__(256) void transpose_bf16(const unsigned short* __restrict__ in,
                                                      unsigned short* __restrict__ out,
                                                      int n) {
  __shared__ unsigned short t[64][65];
  int nb = n >> 6;
  int bx = blockIdx.x % nb, by = blockIdx.x / nb;
  int r0 = by << 6, c0 = bx << 6;
  for (int it = 0; it < 16; ++it) {
    int idx = (it << 8) + threadIdx.x;
    int r = idx >> 6, c = idx & 63;
    t[r][c] = in[(size_t)(r0 + r) * n + c0 + c];
  }
  __syncthreads();
  for (int it = 0; it < 16; ++it) {
    int idx = (it << 8) + threadIdx.x;
    int r = idx >> 6, c = idx & 63;
    out[(size_t)(c0 + r) * n + r0 + c] = t[c][r];
  }
}

// theta[K][N] f32 -> thetaT[N][K] bf16
__global__ void conv_T_bf16(const float* __restrict__ in, unsigned short* __restrict__ outp,
                            int K, int N) {
  int idx = blockIdx.x * blockDim.x + threadIdx.x;
  if (idx >= K * N) return;
  int k = idx / N, n = idx % N;
  outp[(size_t)n * K + k] = f2bf(in[idx]);
}

// ---------------- sparse aggregation (score-critical path, fp32) ------------
__global__ void gcn_epi_sparse(const float* __restrict__ U2, const int* __restrict__ perm,
                               const float* __restrict__ diag2, const float* __restrict__ Z,
                               const float* __restrict__ dinv, const float* __restrict__ bias,
                               float* __restrict__ outp, int C, int total) {
  int idx = blockIdx.x * blockDim.x + threadIdx.x;
  if (idx >= total) return;
  int r = idx / C, c = idx % C;
  int p = perm[r];
  float v = U2[(size_t)p * C + c] + (1.f - diag2[p]) * Z[idx];
  outp[idx] = fmaxf(dinv[r] * v + bias[c], 0.f);
}

template <int C>
__global__ __launch_bounds__(256) void atspmm_g(const int* __restrict__ iptr,
                                                const int* __restrict__ isrc,
                                                const int* __restrict__ rank,
                                                const float* __restrict__ Zc,
                                                float* __restrict__ Zout) {
  constexpr int L = C / 4;
  int li = threadIdx.x % L;
  int i = blockIdx.x * (256 / L) + threadIdx.x / L;
  float4 acc = make_float4(0.f, 0.f, 0.f, 0.f);
  int r0 = rank[i];
  if (r0 >= 0) acc = *(const float4*)(Zc + (size_t)r0 * C + li * 4);
  int beg = iptr[i], end = iptr[i + 1];
  for (int e = beg; e < end; ++e) {
    int rs = rank[isrc[e]];
    if (rs >= 0) {
      float4 z = *(const float4*)(Zc + (size_t)rs * C + li * 4);
      acc.x += z.x; acc.y += z.y; acc.z += z.z; acc.w += z.w;
    }
  }
  *(float4*)(Zout + (size_t)i * C + li * 4) = acc;
}

template <int C>
__global__ __launch_bounds__(256) void atspmm4(const int* __restrict__ iptr,
                                               const int* __restrict__ isrc,
                                               const float* __restrict__ Zin,
                                               float* __restrict__ Zout) {
  constexpr int L = C / 4;
  int li = threadIdx.x % L;
  int i = blockIdx.x * (256 / L) + threadIdx.x / L;
  float4 acc = *(const float4*)(Zin + (size_t)i * C + li * 4);
  int beg = iptr[i], end = iptr[i + 1];
  for (int e = beg; e < end; ++e) {
    float4 z = *(const float4*)(Zin + (size_t)isrc[e] * C + li * 4);
    acc.x += z.x; acc.y += z.y; acc.z += z.z; acc.w += z.w;
  }
  *(float4*)(Zout + (size_t)i * C + li * 4) = acc;
}

template <int C>
__global__ __launch_bounds__(256) void gcn_spmm4(const int* __restrict__ iptr,
                                                 const int* __restrict__ isrc,
                                                 const float* __restrict__ Z,
                                                 const float* __restrict__ dinv,
                                                 const float* __restrict__ bias,
                                                 float* __restrict__ outp) {
  constexpr int L = C / 4;
  int li = threadIdx.x % L;
  int i = blockIdx.x * (256 / L) + threadIdx.x / L;
  float4 acc = *(const float4*)(Z + (size_t)i * C + li * 4);
  int beg = iptr[i], end = iptr[i + 1];
  for (int e = beg; e < end; ++e) {
    float4 z = *(const float4*)(Z + (size_t)isrc[e] * C + li * 4);
    acc.x += z.x; acc.y += z.y; acc.z += z.z; acc.w += z.w;
  }
  float d = dinv[i];
  float4 bb = *(const float4*)(bias + li * 4);
  float4 o;
  o.x = fmaxf(d * acc.x + bb.x, 0.f);
  o.y = fmaxf(d * acc.y + bb.y, 0.f);
  o.z = fmaxf(d * acc.z + bb.z, 0.f);
  o.w = fmaxf(d * acc.w + bb.w, 0.f);
  *(float4*)(outp + (size_t)i * C + li * 4) = o;
}

__global__ void gather_scale(const float* __restrict__ X, const int* __restrict__ perm,
                             const float* __restrict__ vals, float* __restrict__ outp,
                             int C, int total) {
  int idx = blockIdx.x * blockDim.x + threadIdx.x;
  if (idx >= total) return;
  int a = idx / C, c = idx % C;
  outp[idx] = X[(size_t)perm[a] * C + c] * vals[a];
}

__global__ void add_up(const float* base, const int* __restrict__ rank,
                       const float* __restrict__ up, float* outp, int C, int total) {
  int idx = blockIdx.x * blockDim.x + threadIdx.x;
  if (idx >= total) return;
  int r = idx / C, c = idx % C;
  int rk = rank[r];
  float v = base[idx];
  if (rk >= 0) v += up[(size_t)rk * C + c];
  outp[idx] = v;
}

__global__ void score_kernel(const float* __restrict__ X, int C,
                             const float* __restrict__ p, float* __restrict__ sc) {
  int i = blockIdx.x;
  float s1 = 0.f, s2 = 0.f;
  for (int c = threadIdx.x; c < C; c += blockDim.x) {
    float pv = p[c];
    s1 += pv * pv;
    s2 += X[(size_t)i * C + c] * pv;
  }
  float r1 = blockReduceSum256(s1);
  __syncthreads();
  float r2 = blockReduceSum256(s2);
  if (threadIdx.x == 0) sc[i] = tanhf(r2 / sqrtf(r1));
}

// ---- top-k via radix select (exact value threshold + index-ordered ties) ----
__global__ __launch_bounds__(1024) void topk_select(const float* __restrict__ score,
                                                    int n, int k, int* __restrict__ perm,
                                                    float* __restrict__ vals,
                                                    int* __restrict__ rank) {
  __shared__ unsigned int keys[4096];
  __shared__ int hist[256];
  __shared__ int wsums[16];
  __shared__ unsigned int sh_prefix;
  __shared__ int sh_rem;
  int t = threadIdx.x;
  int m = n >> 10;
  for (int i = t; i < n; i += 1024) {
    unsigned int u = __float_as_uint(score[i]);
    keys[i] = u ^ ((unsigned int)((int)u >> 31) | 0x80000000u);
  }
  if (t == 0) { sh_prefix = 0u; sh_rem = k; }
  __syncthreads();
  for (int round = 0; round < 4; ++round) {
    int shift = 24 - (round << 3);
    if (t < 256) hist[t] = 0;
    __syncthreads();
    unsigned int prefix = sh_prefix;
    unsigned int maskhi = (round == 0) ? 0u : (0xFFFFFFFFu << (shift + 8));
    for (int i = t; i < n; i += 1024) {
      unsigned int kk = keys[i];
      if ((kk & maskhi) == prefix) atomicAdd(&hist[(kk >> shift) & 255], 1);
    }
    __syncthreads();
    if (t == 0) {
      int rem = sh_rem, acc = 0, b = 255;
      for (; b > 0; --b) {
        if (acc + hist[b] >= rem) break;
        acc += hist[b];
      }
      sh_rem = rem - acc;
      sh_prefix = prefix | ((unsigned int)b << shift);
    }
    __syncthreads();
  }
  unsigned int thr = sh_prefix;
  int need = sh_rem;
  int base = t * m;
  int f[4];
  int cnt = 0;
#pragma unroll
  for (int j = 0; j < 4; ++j) {
    f[j] = 0;
    if (j < m) { f[j] = (keys[base + j] == thr) ? 1 : 0; cnt += f[j]; }
  }
  int ex = blockScanExclusive(cnt, wsums);
  int sel[4];
  int scnt = 0;
#pragma unroll
  for (int j = 0; j < 4; ++j) {
    sel[j] = 0;
    if (j < m) {
      unsigned int kk = keys[base + j];
      sel[j] = (kk > thr) || (kk == thr && ex < need);
      ex += f[j];
      scnt += sel[j];
    }
  }
  int pos = blockScanExclusive(scnt, wsums);
#pragma unroll
  for (int j = 0; j < 4; ++j) {
    if (j < m) {
      int i = base + j;
      if (sel[j]) {
        unsigned int kk = keys[i];
        unsigned int u = (kk & 0x80000000u) ? (kk ^ 0x80000000u) : ~kk;
        perm[pos] = i;
        vals[pos] = __uint_as_float(u);
        rank[i] = pos;
        pos++;
      } else {
        rank[i] = -1;
      }
    }
  }
}

// W1[a,b] (bf16, integer-exact) + dinv1
__global__ void build_W1(const int* __restrict__ optr, const int* __restrict__ odst,
                         const int* __restrict__ perm1, const int* __restrict__ rank1,
                         unsigned short* __restrict__ W1b, float* __restrict__ dinv1) {
  __shared__ float row[2048];
  int a = blockIdx.x;
  int pa = perm1[a];
  for (int i = threadIdx.x; i < 2048; i += blockDim.x) row[i] = 0.f;
  __syncthreads();
  int kbeg = optr[pa], kend = optr[pa + 1];
  for (int kk = kbeg - 1; kk < kend; ++kk) {
    int k = (kk < kbeg) ? pa : odst[kk];
    int jbeg = optr[k], jend = optr[k + 1];
    for (int jj = jbeg - 1 + (int)threadIdx.x; jj < jend; jj += (int)blockDim.x) {
      int j = (jj < jbeg) ? k : odst[jj];
      int rb = rank1[j];
      if (rb >= 0) atomicAdd(&row[rb], 1.0f);
    }
  }
  __syncthreads();
  float ssum = 0.f;
  for (int i = threadIdx.x; i < 2048; i += blockDim.x) {
    float v = (i == a) ? 0.f : row[i];
    W1b[(size_t)a * 2048 + i] = f2bf(v);
    ssum += v;
  }
  float t = blockReduceSum256(ssum);
  if (threadIdx.x == 0) dinv1[a] = rsqrtf(t + 1.0f);
}

__global__ void mean_cols(const float* __restrict__ X, int R, int C, float* __restrict__ outp) {
  int c = blockIdx.x;
  float s = 0.f;
  for (int r = threadIdx.x; r < R; r += blockDim.x) s += X[(size_t)r * C + c];
  float t = blockReduceSum256(s);
  if (threadIdx.x == 0) outp[c] = t / (float)R;
}

// ---------------- launcher ----------------
extern "C" void kernel_launch(void* const* d_in, const int* in_sizes, int n_in,
                              void* d_out, int out_size, void* d_ws, size_t ws_size,
                              hipStream_t stream) {
  const float* x      = (const float*)d_in[0];
  const int*   eidx   = (const int*)d_in[1];
  const float* theta0 = (const float*)d_in[2];
  const float* b0     = (const float*)d_in[3];
  const float* theta1 = (const float*)d_in[4];
  const float* b1     = (const float*)d_in[5];
  const float* theta2 = (const float*)d_in[6];
  const float* b2     = (const float*)d_in[7];
  const float* theta3 = (const float*)d_in[8];
  const float* b3     = (const float*)d_in[9];
  const float* theta4 = (const float*)d_in[10];
  const float* b4     = (const float*)d_in[11];
  const float* p1     = (const float*)d_in[12];
  const float* p2     = (const float*)d_in[13];
  const int E = in_sizes[1] / 2;
  const int* src = eidx;
  const int* dst = eidx + E;
  float* out = (float*)d_out;

  char* wsb = (char*)d_ws;
  size_t off = 0;
  auto alloc = [&](size_t bytes) -> void* {
    void* p = wsb + off;
    off = (off + bytes + 255) & ~(size_t)255;
    return p;
  };
  int* optr  = (int*)alloc((N0 + 1) * 4);
  int* iptr  = (int*)alloc((N0 + 1) * 4);
  int* odst  = (int*)alloc((size_t)E * 4);
  int* isrc  = (int*)alloc((size_t)E * 4);
  int* cnt4  = (int*)alloc((size_t)4 * N0 * 4);
  int* perm1 = (int*)alloc(P1K * 4);
  int* rank1 = (int*)alloc(N0 * 4);
  int* perm2 = (int*)alloc(P2K * 4);
  int* rank2 = (int*)alloc(P1K * 4);
  float* dinv0 = (float*)alloc(N0 * 4);
  float* dinv1 = (float*)alloc(P1K * 4);
  float* dinv2 = (float*)alloc(P2K * 4);
  float* vals1 = (float*)alloc(P1K * 4);
  float* vals2 = (float*)alloc(P2K * 4);
  float* score = (float*)alloc(N0 * 4);
  float* diag2 = (float*)alloc(N0 * 4);
  float* degsum2 = (float*)alloc(P2K * 4);
  float* x0  = (float*)alloc((size_t)N0 * 256 * 4);
  float* x1  = (float*)alloc((size_t)P1K * 256 * 4);
  float* x1b = (float*)alloc((size_t)P1K * 512 * 4);
  float* x2  = (float*)alloc((size_t)P2K * 512 * 4);
  float* xb  = (float*)alloc((size_t)P2K * 512 * 4);
  float* xu  = (float*)alloc((size_t)P1K * 256 * 4);
  float* SA  = (float*)alloc((size_t)P1K * 512 * 4);   // Z scratch (fp32)
  float* ZF  = (float*)alloc((size_t)N0 * 512 * 4);    // 2-hop U2
  float* ZU  = (float*)alloc((size_t)N0 * 512 * 4);    // 2-hop U1
  unsigned short* W1b  = (unsigned short*)alloc((size_t)P1K * P1K * 2);
  unsigned short* W1bT = (unsigned short*)alloc((size_t)P1K * P1K * 2);
  unsigned short* W2Tb = (unsigned short*)alloc((size_t)P2K * P2K * 2);
  unsigned short* SAbT = (unsigned short*)alloc((size_t)524288 * 2);  // Zc^T bf16
  unsigned short* t2T  = (unsigned short*)alloc((size_t)512 * 512 * 2);
  unsigned short* t3T  = (unsigned short*)alloc((size_t)256 * 512 * 2);
  unsigned short* t4T  = (unsigned short*)alloc((size_t)128 * 256 * 2);
  (void)ws_size; (void)n_in; (void)out_size;

  int* co = cnt4;
  int* ci = cnt4 + N0;
  int* fo = cnt4 + 2 * N0;
  int* fi = cnt4 + 3 * N0;

  // --- graph build ---
  hipMemsetAsync(cnt4, 0, (size_t)4 * N0 * 4, stream);
  hipMemsetAsync(degsum2, 0, (size_t)P2K * 4, stream);
  count_edges<<<E / 256, 256, 0, stream>>>(src, dst, co, ci, E);
  exscan4096<<<1, 1024, 0, stream>>>(co, optr);
  exscan4096<<<1, 1024, 0, stream>>>(ci, iptr);
  fill_edges<<<E / 256, 256, 0, stream>>>(src, dst, optr, iptr, fo, fi, odst, isrc, E);
  dinv0_kernel<<<N0 / 256, 256, 0, stream>>>(optr, dinv0);
  diag2_kernel<<<N0, 64, 0, stream>>>(optr, odst, diag2);
  // weight transposes (bf16 B-operands)
  conv_T_bf16<<<512 * 512 / 256, 256, 0, stream>>>(theta2, t2T, 512, 512);
  conv_T_bf16<<<512 * 256 / 256, 256, 0, stream>>>(theta3, t3T, 512, 256);
  conv_T_bf16<<<256 * 128 / 256, 256, 0, stream>>>(theta4, t4T, 256, 128);

  // --- gcn0 (score-critical, fp32): x[4096,128] -> x0[4096,256] ---
  mm32<<<(4096 / 32) * (256 / 64), 256, 0, stream>>>(x, theta0, SA, dinv0, 4096, 256, 128);
  gcn_spmm4<256><<<1024, 256, 0, stream>>>(iptr, isrc, SA, dinv0, b0, x0);

  // --- pool 1 ---
  score_kernel<<<4096, 256, 0, stream>>>(x0, 256, p1, score);
  topk_select<<<1, 1024, 0, stream>>>(score, 4096, 2048, perm1, vals1, rank1);
  gather_scale<<<2048 * 256 / 256, 256, 0, stream>>>(x0, perm1, vals1, x1, 256, 2048 * 256);
  build_W1<<<2048, 256, 0, stream>>>(optr, odst, perm1, rank1, W1b, dinv1);
  transpose_bf16<<<(2048 / 64) * (2048 / 64), 256, 0, stream>>>(W1b, W1bT, 2048);

  // --- gcn1 (score-critical, fp32 sparse 2-hop): x1[2048,256] -> x1b[2048,512] ---
  mm32<<<(2048 / 32) * (512 / 64), 256, 0, stream>>>(x1, theta1, SA, dinv1, 2048, 512, 256);
  atspmm_g<512><<<2048, 256, 0, stream>>>(iptr, isrc, rank1, SA, ZU);
  atspmm4<512><<<2048, 256, 0, stream>>>(iptr, isrc, ZU, ZF);
  gcn_epi_sparse<<<2048 * 512 / 256, 256, 0, stream>>>(ZF, perm1, diag2, SA, dinv1, b1,
                                                       x1b, 512, 2048 * 512);

  // --- pool 2 ---
  score_kernel<<<2048, 256, 0, stream>>>(x1b, 512, p2, score);
  topk_select<<<1, 1024, 0, stream>>>(score, 2048, 1024, perm2, vals2, rank2);
  gather_scale<<<1024 * 512 / 256, 256, 0, stream>>>(x1b, perm2, vals2, x2, 512, 1024 * 512);
  mm_w2_mfma<<<16 * 16, 256, 0, stream>>>(W1b, W1bT, perm2, W2Tb, degsum2);
  dinv2_kernel<<<P2K / 256, 256, 0, stream>>>(degsum2, dinv2);

  // --- gcn2 (bottleneck, bf16 MFMA): x2[1024,512] -> xb[1024,512] ---
  gemm_ab<false, 0><<<(1024 / 64) * (512 / 64), 256, 0, stream>>>(
      x2, t2T, nullptr, dinv2, nullptr, SA, SAbT, 1024, 512, 512);
  gemm_ab<true, 1><<<(1024 / 64) * (512 / 64), 256, 0, stream>>>(
      W2Tb, SAbT, SA, dinv2, b2, xb, nullptr, 1024, 512, 1024);
  mean_cols<<<512, 256, 0, stream>>>(xb, 1024, 512, out + 524288);

  // --- up block 1 (bf16 MFMA, dense W1): -> xu[2048,256] ---
  add_up<<<2048 * 512 / 256, 256, 0, stream>>>(x1b, rank2, xb, x1b, 512, 2048 * 512);
  gemm_ab<false, 0><<<(2048 / 64) * (256 / 64), 256, 0, stream>>>(
      x1b, t3T, nullptr, dinv1, nullptr, SA, SAbT, 2048, 256, 512);
  gemm_ab<true, 1><<<(2048 / 64) * (256 / 64), 256, 0, stream>>>(
      W1bT, SAbT, SA, dinv1, b3, xu, nullptr, 2048, 256, 2048);

  // --- up block 0 (bf16 mm + fp32 sparse agg): -> out[4096,128] ---
  add_up<<<4096 * 256 / 256, 256, 0, stream>>>(x0, rank1, xu, x0, 256, 4096 * 256);
  gemm_ab<false, 0><<<(4096 / 64) * (128 / 64), 256, 0, stream>>>(
      x0, t4T, nullptr, dinv0, nullptr, SA, nullptr, 4096, 128, 256);
  gcn_spmm4<128><<<512, 256, 0, stream>>>(iptr, isrc, SA, dinv0, b4, out);
}

// Round 5
// 419.447 us; speedup vs baseline: 2.0872x; 1.1267x over previous
//
#include <hip/hip_runtime.h>

#define N0 4096
#define P1K 2048
#define P2K 1024
#define SPLITS 4

typedef short bf16x8 __attribute__((ext_vector_type(8)));
typedef float f32x4 __attribute__((ext_vector_type(4)));

__device__ __forceinline__ unsigned short f2bf(float f) {
  unsigned int u = __float_as_uint(f);
  unsigned int r = (u + 0x7fff + ((u >> 16) & 1)) >> 16;
  return (unsigned short)r;
}
__device__ __forceinline__ float bf2f(unsigned short h) {
  unsigned int u = ((unsigned int)h) << 16;
  return __uint_as_float(u);
}

// ---------------- helpers ----------------
__device__ __forceinline__ float blockReduceSum256(float v) {
  __shared__ float sh[16];
  int lane = threadIdx.x & 63;
  int w = threadIdx.x >> 6;
#pragma unroll
  for (int o = 32; o > 0; o >>= 1) v += __shfl_down(v, o, 64);
  __syncthreads();
  if (lane == 0) sh[w] = v;
  __syncthreads();
  float r = 0.f;
  if (threadIdx.x == 0) {
    int nw = (blockDim.x + 63) >> 6;
    for (int i = 0; i < nw; ++i) r += sh[i];
  }
  return r;  // valid on thread 0 only
}

__device__ __forceinline__ int blockScanExclusive(int v, volatile int* wsums) {
  int lane = threadIdx.x & 63, w = threadIdx.x >> 6;
  int x = v;
#pragma unroll
  for (int o = 1; o < 64; o <<= 1) {
    int y = __shfl_up(x, o, 64);
    if (lane >= o) x += y;
  }
  if (lane == 63) wsums[w] = x;
  __syncthreads();
  if (threadIdx.x < 64) {
    int nw = blockDim.x >> 6;
    int s = (threadIdx.x < nw) ? wsums[threadIdx.x] : 0;
#pragma unroll
    for (int o = 1; o < 16; o <<= 1) {
      int y = __shfl_up(s, o, 64);
      if (lane >= o) s += y;
    }
    if (threadIdx.x < nw) wsums[threadIdx.x] = s;
  }
  __syncthreads();
  int base = (w > 0) ? wsums[w - 1] : 0;
  __syncthreads();
  return base + x - v;
}

// ---------------- graph build ----------------
__global__ void count_edges(const int* __restrict__ src, const int* __restrict__ dst,
                            int* __restrict__ co, int* __restrict__ ci, int E) {
  int e = blockIdx.x * blockDim.x + threadIdx.x;
  if (e >= E) return;
  atomicAdd(&co[src[e]], 1);
  atomicAdd(&ci[dst[e]], 1);
}

__global__ __launch_bounds__(1024) void exscan4096(const int* __restrict__ cnt,
                                                   int* __restrict__ ptr) {
  __shared__ int ls[1024];
  int t = threadIdx.x;
  int v0 = cnt[t * 4], v1 = cnt[t * 4 + 1], v2 = cnt[t * 4 + 2], v3 = cnt[t * 4 + 3];
  int s = v0 + v1 + v2 + v3;
  ls[t] = s;
  __syncthreads();
  for (int off = 1; off < 1024; off <<= 1) {
    int x = (t >= off) ? ls[t - off] : 0;
    __syncthreads();
    ls[t] += x;
    __syncthreads();
  }
  int ex = (t > 0) ? ls[t - 1] : 0;
  ptr[t * 4]     = ex;
  ptr[t * 4 + 1] = ex + v0;
  ptr[t * 4 + 2] = ex + v0 + v1;
  ptr[t * 4 + 3] = ex + v0 + v1 + v2;
  if (t == 1023) ptr[4096] = ex + s;
}

__global__ void fill_edges(const int* __restrict__ src, const int* __restrict__ dst,
                           const int* __restrict__ optr, const int* __restrict__ iptr,
                           int* __restrict__ fo, int* __restrict__ fi,
                           int* __restrict__ odst, int* __restrict__ isrc, int E) {
  int e = blockIdx.x * blockDim.x + threadIdx.x;
  if (e >= E) return;
  int s = src[e], d = dst[e];
  odst[optr[s] + atomicAdd(&fo[s], 1)] = d;
  isrc[iptr[d] + atomicAdd(&fi[d], 1)] = s;
}

__global__ void dinv0_kernel(const int* __restrict__ optr, float* __restrict__ dinv0) {
  int i = blockIdx.x * blockDim.x + threadIdx.x;
  if (i < N0) dinv0[i] = rsqrtf((float)(optr[i + 1] - optr[i]) + 1.0f);
}

__global__ __launch_bounds__(64) void diag2_kernel(const int* __restrict__ optr,
                                                   const int* __restrict__ odst,
                                                   float* __restrict__ diag2) {
  int i = blockIdx.x;
  int cnt = 0;
  int kbeg = optr[i], kend = optr[i + 1];
  for (int kk = kbeg - 1; kk < kend; ++kk) {
    int k = (kk < kbeg) ? i : odst[kk];
    int jbeg = optr[k], jend = optr[k + 1];
    for (int jj = jbeg - 1 + (int)threadIdx.x; jj < jend; jj += 64) {
      int j = (jj < jbeg) ? k : odst[jj];
      if (j == i) cnt++;
    }
  }
#pragma unroll
  for (int o = 32; o > 0; o >>= 1) cnt += __shfl_down(cnt, o, 64);
  if (threadIdx.x == 0) diag2[i] = (float)cnt;
}

// ---- fp32 score-critical GEMM: 32x64 tile, optional fused row-gather+scale ----
__global__ __launch_bounds__(256) void mm32(const float* __restrict__ A,
                                            const float* __restrict__ B,
                                            float* __restrict__ C,
                                            const float* __restrict__ dinv,
                                            const int* __restrict__ permA,
                                            const float* __restrict__ valsA,
                                            int M, int N, int K) {
  __shared__ float As[16][32];
  __shared__ float Bs[16][64];
  int tid = threadIdx.x;
  int nbx = N >> 6;
  int by = blockIdx.x / nbx, bx = blockIdx.x % nbx;
  int row0 = by << 5, col0 = bx << 6;
  int tx = tid & 15, ty = tid >> 4;
  float acc[2][4] = {{0.f}};
  for (int k0 = 0; k0 < K; k0 += 16) {
    {
      int r = tid >> 3;
      int row = row0 + r;
      int srow = permA ? permA[row] : row;
      float vs = valsA ? valsA[row] : 1.f;
      int kk = (tid & 7) << 1;
      float2 v = *(const float2*)(A + (size_t)srow * K + k0 + kk);
      As[kk][r] = v.x * vs;
      As[kk + 1][r] = v.y * vs;
    }
#pragma unroll
    for (int p = 0; p < 4; ++p) {
      int kk = (tid >> 6) + (p << 2);
      int c = tid & 63;
      Bs[kk][c] = B[(size_t)(k0 + kk) * N + col0 + c];
    }
    __syncthreads();
#pragma unroll
    for (int kk = 0; kk < 16; ++kk) {
      float a0 = As[kk][ty << 1], a1 = As[kk][(ty << 1) + 1];
      float4 b = *(const float4*)&Bs[kk][tx << 2];
      acc[0][0] += a0 * b.x; acc[0][1] += a0 * b.y;
      acc[0][2] += a0 * b.z; acc[0][3] += a0 * b.w;
      acc[1][0] += a1 * b.x; acc[1][1] += a1 * b.y;
      acc[1][2] += a1 * b.z; acc[1][3] += a1 * b.w;
    }
    __syncthreads();
  }
#pragma unroll
  for (int i = 0; i < 2; ++i) {
    int r = row0 + (ty << 1) + i;
    float dv = dinv ? dinv[r] : 1.f;
#pragma unroll
    for (int j = 0; j < 4; ++j) C[(size_t)r * N + col0 + (tx << 2) + j] = acc[i][j] * dv;
  }
}

// ---- split-K bf16 MFMA GEMM: Pf[s][M][N] partials; B transposed bf16 BT[N][K] ----
// ABF16=0: A fp32 with optional row gather (permA) + scale (valsA), converted on load.
template <bool ABF16>
__global__ __launch_bounds__(256) void gemm_sk(const void* __restrict__ Av,
                                               const unsigned short* __restrict__ BT,
                                               const int* __restrict__ permA,
                                               const float* __restrict__ valsA,
                                               float* __restrict__ Pf,
                                               int M, int N, int K, int nbx, int nb2d) {
  __shared__ unsigned short As[64 * 64];
  __shared__ unsigned short Bs[64 * 64];
  int tid = threadIdx.x;
  int s = blockIdx.x / nb2d;
  int r2 = blockIdx.x % nb2d;
  int by = r2 / nbx, bx = r2 % nbx;
  int row0 = by << 6, col0 = bx << 6;
  int kc = K / SPLITS;
  int ks = s * kc, ke = ks + kc;
  int l = tid & 63, wv = tid >> 6;
  int wr = (wv >> 1) << 5, wc = (wv & 1) << 5;
  f32x4 acc[2][2] = {};
  for (int k0 = ks; k0 < ke; k0 += 64) {
#pragma unroll
    for (int it = 0; it < 2; ++it) {
      int idx = (it << 8) + tid;
      int r = idx >> 3, c8 = idx & 7;
      int sw = c8 ^ (r & 7);
      if (ABF16) {
        ((uint4*)As)[(r << 3) + sw] =
            *(const uint4*)((const unsigned short*)Av + (size_t)(row0 + r) * K + k0 + (c8 << 3));
      } else {
        int row = row0 + r;
        int srow = permA ? permA[row] : row;
        float vs = valsA ? valsA[row] : 1.f;
        const float* Af = (const float*)Av + (size_t)srow * K + k0 + (c8 << 3);
        float4 f0 = *(const float4*)Af;
        float4 f1 = *(const float4*)(Af + 4);
        uint4 u;
        u.x = (unsigned)f2bf(f0.x * vs) | ((unsigned)f2bf(f0.y * vs) << 16);
        u.y = (unsigned)f2bf(f0.z * vs) | ((unsigned)f2bf(f0.w * vs) << 16);
        u.z = (unsigned)f2bf(f1.x * vs) | ((unsigned)f2bf(f1.y * vs) << 16);
        u.w = (unsigned)f2bf(f1.z * vs) | ((unsigned)f2bf(f1.w * vs) << 16);
        ((uint4*)As)[(r << 3) + sw] = u;
      }
      ((uint4*)Bs)[(r << 3) + sw] =
          *(const uint4*)(BT + (size_t)(col0 + r) * K + k0 + (c8 << 3));
    }
    __syncthreads();
#pragma unroll
    for (int kk2 = 0; kk2 < 2; ++kk2) {
      int ch = (kk2 << 2) + (l >> 4);
      int ra = wr + (l & 15), rb = ra + 16;
      int ca = wc + (l & 15), cb = ca + 16;
      bf16x8 a0 = *(const bf16x8*)&As[(ra << 6) + ((ch ^ (ra & 7)) << 3)];
      bf16x8 a1 = *(const bf16x8*)&As[(rb << 6) + ((ch ^ (rb & 7)) << 3)];
      bf16x8 b0 = *(const bf16x8*)&Bs[(ca << 6) + ((ch ^ (ca & 7)) << 3)];
      bf16x8 b1 = *(const bf16x8*)&Bs[(cb << 6) + ((ch ^ (cb & 7)) << 3)];
      acc[0][0] = __builtin_amdgcn_mfma_f32_16x16x32_bf16(a0, b0, acc[0][0], 0, 0, 0);
      acc[0][1] = __builtin_amdgcn_mfma_f32_16x16x32_bf16(a0, b1, acc[0][1], 0, 0, 0);
      acc[1][0] = __builtin_amdgcn_mfma_f32_16x16x32_bf16(a1, b0, acc[1][0], 0, 0, 0);
      acc[1][1] = __builtin_amdgcn_mfma_f32_16x16x32_bf16(a1, b1, acc[1][1], 0, 0, 0);
    }
    __syncthreads();
  }
  int lrow = (l >> 4) << 2, lcol = l & 15;
  float* P = Pf + (size_t)s * M * N;
#pragma unroll
  for (int i = 0; i < 2; ++i)
#pragma unroll
    for (int j = 0; j < 2; ++j) {
      int c = col0 + wc + (j << 4) + lcol;
      int r0 = row0 + wr + (i << 4) + lrow;
#pragma unroll
      for (int rg = 0; rg < 4; ++rg)
        P[(size_t)(r0 + rg) * N + c] = acc[i][j][rg];
    }
}

// reduce partials, scale by dinv, write Cf fp32 + optional transposed bf16 CbT
__global__ __launch_bounds__(256) void epi_red0_t(const float* __restrict__ Pf,
                                                  const float* __restrict__ dinv,
                                                  float* __restrict__ Cf,
                                                  unsigned short* __restrict__ CbT,
                                                  int M, int N) {
  __shared__ float t[64][65];
  int nbx = N >> 6;
  int by = blockIdx.x / nbx, bx = blockIdx.x % nbx;
  int r0 = by << 6, c0 = bx << 6;
  size_t MN = (size_t)M * N;
  for (int it = 0; it < 16; ++it) {
    int idx = (it << 8) + threadIdx.x;
    int r = idx >> 6, c = idx & 63;
    size_t o = (size_t)(r0 + r) * N + c0 + c;
    float v = 0.f;
#pragma unroll
    for (int s = 0; s < SPLITS; ++s) v += Pf[s * MN + o];
    v *= dinv ? dinv[r0 + r] : 1.f;
    Cf[o] = v;
    t[r][c] = v;
  }
  __syncthreads();
  if (CbT) {
    for (int it = 0; it < 16; ++it) {
      int idx = (it << 8) + threadIdx.x;
      int rr = idx >> 6, cc = idx & 63;
      CbT[(size_t)(c0 + rr) * M + r0 + cc] = f2bf(t[cc][rr]);
    }
  }
}

// reduce partials + GCN epilogue: out = relu(dinv[r]*(sum + Zadd) + bias)
__global__ __launch_bounds__(256) void epi_red1(const float* __restrict__ Pf,
                                                const float* __restrict__ Zadd,
                                                const float* __restrict__ dinv,
                                                const float* __restrict__ bias,
                                                float* __restrict__ outp, int M, int N) {
  int g = blockIdx.x * 256 + threadIdx.x;
  size_t base = (size_t)g * 4;
  size_t MN = (size_t)M * N;
  if (base >= MN) return;
  int r = (int)(base / N), c = (int)(base % N);
  float4 a = *(const float4*)&Pf[base];
#pragma unroll
  for (int s = 1; s < SPLITS; ++s) {
    float4 p = *(const float4*)&Pf[s * MN + base];
    a.x += p.x; a.y += p.y; a.z += p.z; a.w += p.w;
  }
  float4 z = *(const float4*)&Zadd[base];
  float dv = dinv[r];
  float4 bb = *(const float4*)&bias[c];
  float4 o;
  o.x = fmaxf(dv * (a.x + z.x) + bb.x, 0.f);
  o.y = fmaxf(dv * (a.y + z.y) + bb.y, 0.f);
  o.z = fmaxf(dv * (a.z + z.z) + bb.z, 0.f);
  o.w = fmaxf(dv * (a.w + z.w) + bb.w, 0.f);
  *(float4*)&outp[base] = o;
}

// ---- W2f += A1[p2,:]@A1[:,p2] split-K, fp32 atomics (integer-exact) ----
__global__ __launch_bounds__(256) void mm_w2_mfma(const unsigned short* __restrict__ Wb,
                                                  const unsigned short* __restrict__ WbT,
                                                  const int* __restrict__ perm2,
                                                  float* __restrict__ W2f) {
  __shared__ unsigned short As[64 * 64];
  __shared__ unsigned short Bs[64 * 64];
  __shared__ int pr[64], pc[64];
  int tid = threadIdx.x;
  int s = blockIdx.x >> 8;
  int t2d = blockIdx.x & 255;
  int bx = t2d & 15, by = t2d >> 4;
  int row0 = by << 6, col0 = bx << 6;
  int ks = s * (2048 / SPLITS), ke = ks + 2048 / SPLITS;
  if (tid < 64) pr[tid] = perm2[row0 + tid];
  else if (tid < 128) pc[tid - 64] = perm2[col0 + tid - 128 + 64];
  __syncthreads();
  int l = tid & 63, wv = tid >> 6;
  int wr = (wv >> 1) << 5, wc = (wv & 1) << 5;
  f32x4 acc[2][2] = {};
  for (int k0 = ks; k0 < ke; k0 += 64) {
#pragma unroll
    for (int it = 0; it < 2; ++it) {
      int idx = (it << 8) + tid;
      int r = idx >> 3, c8 = idx & 7;
      int sw = c8 ^ (r & 7);
      ((uint4*)As)[(r << 3) + sw] =
          *(const uint4*)(Wb + (size_t)pr[r] * 2048 + k0 + (c8 << 3));
      ((uint4*)Bs)[(r << 3) + sw] =
          *(const uint4*)(WbT + (size_t)pc[r] * 2048 + k0 + (c8 << 3));
    }
    __syncthreads();
    if (tid < 64) {
      int r = tid, d = pr[r] - k0;
      if (d >= 0 && d < 64) {
        int ui = (r << 6) + (((d >> 3) ^ (r & 7)) << 3) + (d & 7);
        As[ui] = f2bf(bf2f(As[ui]) + 1.f);
      }
    } else if (tid < 128) {
      int c = tid - 64, d = pc[c] - k0;
      if (d >= 0 && d < 64) {
        int ui = (c << 6) + (((d >> 3) ^ (c & 7)) << 3) + (d & 7);
        Bs[ui] = f2bf(bf2f(Bs[ui]) + 1.f);
      }
    }
    __syncthreads();
#pragma unroll
    for (int kk2 = 0; kk2 < 2; ++kk2) {
      int ch = (kk2 << 2) + (l >> 4);
      int ra = wr + (l & 15), rb = ra + 16;
      int ca = wc + (l & 15), cb = ca + 16;
      bf16x8 a0 = *(const bf16x8*)&As[(ra << 6) + ((ch ^ (ra & 7)) << 3)];
      bf16x8 a1 = *(const bf16x8*)&As[(rb << 6) + ((ch ^ (rb & 7)) << 3)];
      bf16x8 b0 = *(const bf16x8*)&Bs[(ca << 6) + ((ch ^ (ca & 7)) << 3)];
      bf16x8 b1 = *(const bf16x8*)&Bs[(cb << 6) + ((ch ^ (cb & 7)) << 3)];
      acc[0][0] = __builtin_amdgcn_mfma_f32_16x16x32_bf16(a0, b0, acc[0][0], 0, 0, 0);
      acc[0][1] = __builtin_amdgcn_mfma_f32_16x16x32_bf16(a0, b1, acc[0][1], 0, 0, 0);
      acc[1][0] = __builtin_amdgcn_mfma_f32_16x16x32_bf16(a1, b0, acc[1][0], 0, 0, 0);
      acc[1][1] = __builtin_amdgcn_mfma_f32_16x16x32_bf16(a1, b1, acc[1][1], 0, 0, 0);
    }
    __syncthreads();
  }
  int lrow = (l >> 4) << 2, lcol = l & 15;
#pragma unroll
  for (int i = 0; i < 2; ++i)
#pragma unroll
    for (int j = 0; j < 2; ++j) {
      int c = col0 + wc + (j << 4) + lcol;
      int r0 = row0 + wr + (i << 4) + lrow;
#pragma unroll
      for (int rg = 0; rg < 4; ++rg)
        atomicAdd(&W2f[(size_t)(r0 + rg) * 1024 + c], acc[i][j][rg]);
    }
}

// W2f (exact fp32) -> W2Tb bf16 transposed, diag zeroed, exact row sums
__global__ __launch_bounds__(256) void w2_post(const float* __restrict__ W2f,
                                               unsigned short* __restrict__ W2Tb,
                                               float* __restrict__ degsum2) {
  __shared__ float t[64][65];
  int bx = blockIdx.x & 15, by = blockIdx.x >> 4;
  int r0 = by << 6, c0 = bx << 6;
  for (int it = 0; it < 16; ++it) {
    int idx = (it << 8) + threadIdx.x;
    int r = idx >> 6, c = idx & 63;
    float v = W2f[(size_t)(r0 + r) * 1024 + c0 + c];
    if (r0 + r == c0 + c) v = 0.f;
    t[r][c] = v;
  }
  __syncthreads();
  if (threadIdx.x < 64) {
    float s = 0.f;
    for (int c = 0; c < 64; ++c) s += t[threadIdx.x][c];
    atomicAdd(&degsum2[r0 + threadIdx.x], s);  // integers: exact, order-free
  }
  for (int it = 0; it < 16; ++it) {
    int idx = (it << 8) + threadIdx.x;
    int rr = idx >> 6, cc = idx & 63;
    W2Tb[(size_t)(c0 + rr) * 1024 + r0 + cc] = f2bf(t[cc][rr]);
  }
}

__global__ void dinv2_kernel(const float* __restrict__ degsum2, float* __restrict__ dinv2) {
  int i = blockIdx.x * blockDim.x + threadIdx.x;
  if (i < P2K) dinv2[i] = rsqrtf(degsum2[i] + 1.0f);
}

// 64x64-tile bf16 transpose
__global__ __launch_bounds__(256) void transpose_bf16(const unsigned short* __restrict__ in,
                                                      unsigned short* __restrict__ out,
                                                      int n) {
  __shared__ unsigned short t[64][65];
  int nb = n >> 6;
  int bx = blockIdx.x % nb, by = blockIdx.x / nb;
  int r0 = by << 6, c0 = bx << 6;
  for (int it = 0; it < 16; ++it) {
    int idx = (it << 8) + threadIdx.x;
    int r = idx >> 6, c = idx & 63;
    t[r][c] = in[(size_t)(r0 + r) * n + c0 + c];
  }
  __syncthreads();
  for (int it = 0; it < 16; ++it) {
    int idx = (it << 8) + threadIdx.x;
    int r = idx >> 6, c = idx & 63;
    out[(size_t)(c0 + r) * n + r0 + c] = t[c][r];
  }
}

__global__ void conv_T_bf16(const float* __restrict__ in, unsigned short* __restrict__ outp,
                            int K, int N) {
  int idx = blockIdx.x * blockDim.x + threadIdx.x;
  if (idx >= K * N) return;
  int k = idx / N, n = idx % N;
  outp[(size_t)n * K + k] = f2bf(in[idx]);
}

// ---------------- sparse aggregation (score-critical path, fp32) ------------
// pass 1 with fused rank-gather over all N0 rows
template <int C>
__global__ __launch_bounds__(256) void atspmm_g(const int* __restrict__ iptr,
                                                const int* __restrict__ isrc,
                                                const int* __restrict__ rank,
                                                const float* __restrict__ Zc,
                                                float* __restrict__ Zout) {
  constexpr int L = C / 4;
  int li = threadIdx.x % L;
  int i = blockIdx.x * (256 / L) + threadIdx.x / L;
  float4 acc = make_float4(0.f, 0.f, 0.f, 0.f);
  int r0 = rank[i];
  if (r0 >= 0) acc = *(const float4*)(Zc + (size_t)r0 * C + li * 4);
  int beg = iptr[i], end = iptr[i + 1];
  for (int e = beg; e < end; ++e) {
    int rs = rank[isrc[e]];
    if (rs >= 0) {
      float4 z = *(const float4*)(Zc + (size_t)rs * C + li * 4);
      acc.x += z.x; acc.y += z.y; acc.z += z.z; acc.w += z.w;
    }
  }
  *(float4*)(Zout + (size_t)i * C + li * 4) = acc;
}

// pass 2 fused with GCN epilogue, kept rows only:
// out[a] = relu(dinv[a]*( U2[p] + (1-diag2[p])*Zc[a] ) + bias),  U2[p]=ZU[p]+sum_in ZU
template <int C>
__global__ __launch_bounds__(256) void atspmm_epi(const int* __restrict__ iptr,
                                                  const int* __restrict__ isrc,
                                                  const int* __restrict__ perm,
                                                  const float* __restrict__ diag2,
                                                  const float* __restrict__ ZU,
                                                  const float* __restrict__ Zc,
                                                  const float* __restrict__ dinv,
                                                  const float* __restrict__ bias,
                                                  float* __restrict__ outp) {
  constexpr int L = C / 4;
  int li = threadIdx.x % L;
  int a = blockIdx.x * (256 / L) + threadIdx.x / L;
  int p = perm[a];
  float4 acc = *(const float4*)(ZU + (size_t)p * C + li * 4);
  int beg = iptr[p], end = iptr[p + 1];
  for (int e = beg; e < end; ++e) {
    float4 z = *(const float4*)(ZU + (size_t)isrc[e] * C + li * 4);
    acc.x += z.x; acc.y += z.y; acc.z += z.z; acc.w += z.w;
  }
  float w = 1.f - diag2[p];
  float4 zc = *(const float4*)(Zc + (size_t)a * C + li * 4);
  float dv = dinv[a];
  float4 bb = *(const float4*)(bias + li * 4);
  float4 o;
  o.x = fmaxf(dv * (acc.x + w * zc.x) + bb.x, 0.f);
  o.y = fmaxf(dv * (acc.y + w * zc.y) + bb.y, 0.f);
  o.z = fmaxf(dv * (acc.z + w * zc.z) + bb.z, 0.f);
  o.w = fmaxf(dv * (acc.w + w * zc.w) + bb.w, 0.f);
  *(float4*)(outp + (size_t)a * C + li * 4) = o;
}

template <int C>
__global__ __launch_bounds__(256) void gcn_spmm4(const int* __restrict__ iptr,
                                                 const int* __restrict__ isrc,
                                                 const float* __restrict__ Z,
                                                 const float* __restrict__ dinv,
                                                 const float* __restrict__ bias,
                                                 float* __restrict__ outp) {
  constexpr int L = C / 4;
  int li = threadIdx.x % L;
  int i = blockIdx.x * (256 / L) + threadIdx.x / L;
  float4 acc = *(const float4*)(Z + (size_t)i * C + li * 4);
  int beg = iptr[i], end = iptr[i + 1];
  for (int e = beg; e < end; ++e) {
    float4 z = *(const float4*)(Z + (size_t)isrc[e] * C + li * 4);
    acc.x += z.x; acc.y += z.y; acc.z += z.z; acc.w += z.w;
  }
  float d = dinv[i];
  float4 bb = *(const float4*)(bias + li * 4);
  float4 o;
  o.x = fmaxf(d * acc.x + bb.x, 0.f);
  o.y = fmaxf(d * acc.y + bb.y, 0.f);
  o.z = fmaxf(d * acc.z + bb.z, 0.f);
  o.w = fmaxf(d * acc.w + bb.w, 0.f);
  *(float4*)(outp + (size_t)i * C + li * 4) = o;
}

__global__ void add_up(const float* base, const int* __restrict__ rank,
                       const float* __restrict__ up, float* outp, int C, int total) {
  int idx = blockIdx.x * blockDim.x + threadIdx.x;
  if (idx >= total) return;
  int r = idx / C, c = idx % C;
  int rk = rank[r];
  float v = base[idx];
  if (rk >= 0) v += up[(size_t)rk * C + c];
  outp[idx] = v;
}

__global__ void score_kernel(const float* __restrict__ X, int C,
                             const float* __restrict__ p, float* __restrict__ sc) {
  int i = blockIdx.x;
  float s1 = 0.f, s2 = 0.f;
  for (int c = threadIdx.x; c < C; c += blockDim.x) {
    float pv = p[c];
    s1 += pv * pv;
    s2 += X[(size_t)i * C + c] * pv;
  }
  float r1 = blockReduceSum256(s1);
  __syncthreads();
  float r2 = blockReduceSum256(s2);
  if (threadIdx.x == 0) sc[i] = tanhf(r2 / sqrtf(r1));
}

// ---- top-k via radix select (exact value threshold + index-ordered ties) ----
__global__ __launch_bounds__(1024) void topk_select(const float* __restrict__ score,
                                                    int n, int k, int* __restrict__ perm,
                                                    float* __restrict__ vals,
                                                    int* __restrict__ rank) {
  __shared__ unsigned int keys[4096];
  __shared__ int hist[256];
  __shared__ int wsums[16];
  __shared__ unsigned int sh_prefix;
  __shared__ int sh_rem;
  int t = threadIdx.x;
  int m = n >> 10;
  for (int i = t; i < n; i += 1024) {
    unsigned int u = __float_as_uint(score[i]);
    keys[i] = u ^ ((unsigned int)((int)u >> 31) | 0x80000000u);
  }
  if (t == 0) { sh_prefix = 0u; sh_rem = k; }
  __syncthreads();
  for (int round = 0; round < 4; ++round) {
    int shift = 24 - (round << 3);
    if (t < 256) hist[t] = 0;
    __syncthreads();
    unsigned int prefix = sh_prefix;
    unsigned int maskhi = (round == 0) ? 0u : (0xFFFFFFFFu << (shift + 8));
    for (int i = t; i < n; i += 1024) {
      unsigned int kk = keys[i];
      if ((kk & maskhi) == prefix) atomicAdd(&hist[(kk >> shift) & 255], 1);
    }
    __syncthreads();
    if (t == 0) {
      int rem = sh_rem, acc = 0, b = 255;
      for (; b > 0; --b) {
        if (acc + hist[b] >= rem) break;
        acc += hist[b];
      }
      sh_rem = rem - acc;
      sh_prefix = prefix | ((unsigned int)b << shift);
    }
    __syncthreads();
  }
  unsigned int thr = sh_prefix;
  int need = sh_rem;
  int base = t * m;
  int f[4];
  int cnt = 0;
#pragma unroll
  for (int j = 0; j < 4; ++j) {
    f[j] = 0;
    if (j < m) { f[j] = (keys[base + j] == thr) ? 1 : 0; cnt += f[j]; }
  }
  int ex = blockScanExclusive(cnt, wsums);
  int sel[4];
  int scnt = 0;
#pragma unroll
  for (int j = 0; j < 4; ++j) {
    sel[j] = 0;
    if (j < m) {
      unsigned int kk = keys[base + j];
      sel[j] = (kk > thr) || (kk == thr && ex < need);
      ex += f[j];
      scnt += sel[j];
    }
  }
  int pos = blockScanExclusive(scnt, wsums);
#pragma unroll
  for (int j = 0; j < 4; ++j) {
    if (j < m) {
      int i = base + j;
      if (sel[j]) {
        unsigned int kk = keys[i];
        unsigned int u = (kk & 0x80000000u) ? (kk ^ 0x80000000u) : ~kk;
        perm[pos] = i;
        vals[pos] = __uint_as_float(u);
        rank[i] = pos;
        pos++;
      } else {
        rank[i] = -1;
      }
    }
  }
}

// W1[a,b] (bf16, integer-exact) + dinv1
__global__ void build_W1(const int* __restrict__ optr, const int* __restrict__ odst,
                         const int* __restrict__ perm1, const int* __restrict__ rank1,
                         unsigned short* __restrict__ W1b, float* __restrict__ dinv1) {
  __shared__ float row[2048];
  int a = blockIdx.x;
  int pa = perm1[a];
  for (int i = threadIdx.x; i < 2048; i += blockDim.x) row[i] = 0.f;
  __syncthreads();
  int kbeg = optr[pa], kend = optr[pa + 1];
  for (int kk = kbeg - 1; kk < kend; ++kk) {
    int k = (kk < kbeg) ? pa : odst[kk];
    int jbeg = optr[k], jend = optr[k + 1];
    for (int jj = jbeg - 1 + (int)threadIdx.x; jj < jend; jj += (int)blockDim.x) {
      int j = (jj < jbeg) ? k : odst[jj];
      int rb = rank1[j];
      if (rb >= 0) atomicAdd(&row[rb], 1.0f);
    }
  }
  __syncthreads();
  float ssum = 0.f;
  for (int i = threadIdx.x; i < 2048; i += blockDim.x) {
    float v = (i == a) ? 0.f : row[i];
    W1b[(size_t)a * 2048 + i] = f2bf(v);
    ssum += v;
  }
  float t = blockReduceSum256(ssum);
  if (threadIdx.x == 0) dinv1[a] = rsqrtf(t + 1.0f);
}

__global__ void mean_cols(const float* __restrict__ X, int R, int C, float* __restrict__ outp) {
  int c = blockIdx.x;
  float s = 0.f;
  for (int r = threadIdx.x; r < R; r += blockDim.x) s += X[(size_t)r * C + c];
  float t = blockReduceSum256(s);
  if (threadIdx.x == 0) outp[c] = t / (float)R;
}

// ---------------- launcher ----------------
extern "C" void kernel_launch(void* const* d_in, const int* in_sizes, int n_in,
                              void* d_out, int out_size, void* d_ws, size_t ws_size,
                              hipStream_t stream) {
  const float* x      = (const float*)d_in[0];
  const int*   eidx   = (const int*)d_in[1];
  const float* theta0 = (const float*)d_in[2];
  const float* b0     = (const float*)d_in[3];
  const float* theta1 = (const float*)d_in[4];
  const float* b1     = (const float*)d_in[5];
  const float* theta2 = (const float*)d_in[6];
  const float* b2     = (const float*)d_in[7];
  const float* theta3 = (const float*)d_in[8];
  const float* b3     = (const float*)d_in[9];
  const float* theta4 = (const float*)d_in[10];
  const float* b4     = (const float*)d_in[11];
  const float* p1     = (const float*)d_in[12];
  const float* p2     = (const float*)d_in[13];
  const int E = in_sizes[1] / 2;
  const int* src = eidx;
  const int* dst = eidx + E;
  float* out = (float*)d_out;

  char* wsb = (char*)d_ws;
  size_t off = 0;
  auto alloc = [&](size_t bytes) -> void* {
    void* p = wsb + off;
    off = (off + bytes + 255) & ~(size_t)255;
    return p;
  };
  int* optr  = (int*)alloc((N0 + 1) * 4);
  int* iptr  = (int*)alloc((N0 + 1) * 4);
  int* odst  = (int*)alloc((size_t)E * 4);
  int* isrc  = (int*)alloc((size_t)E * 4);
  int* cnt4  = (int*)alloc((size_t)4 * N0 * 4);
  int* perm1 = (int*)alloc(P1K * 4);
  int* rank1 = (int*)alloc(N0 * 4);
  int* perm2 = (int*)alloc(P2K * 4);
  int* rank2 = (int*)alloc(P1K * 4);
  float* dinv0 = (float*)alloc(N0 * 4);
  float* dinv1 = (float*)alloc(P1K * 4);
  float* dinv2 = (float*)alloc(P2K * 4);
  float* vals1 = (float*)alloc(P1K * 4);
  float* vals2 = (float*)alloc(P2K * 4);
  float* score = (float*)alloc(N0 * 4);
  float* diag2 = (float*)alloc(N0 * 4);
  float* degsum2 = (float*)alloc(P2K * 4);
  float* x0  = (float*)alloc((size_t)N0 * 256 * 4);
  float* x1b = (float*)alloc((size_t)P1K * 512 * 4);
  float* xb  = (float*)alloc((size_t)P2K * 512 * 4);
  float* xu  = (float*)alloc((size_t)P1K * 256 * 4);
  float* SA  = (float*)alloc((size_t)P1K * 512 * 4);   // Z scratch fp32 (4 MB)
  float* ZU  = (float*)alloc((size_t)N0 * 512 * 4);    // 2-hop pass-1 out (8 MB)
  float* W2f = (float*)alloc((size_t)P2K * P2K * 4);   // fp32 W2 accumulator (4 MB)
  float* Pf  = (float*)alloc((size_t)SPLITS * 524288 * 4);  // split-K partials (8 MB)
  unsigned short* W1b  = (unsigned short*)alloc((size_t)P1K * P1K * 2);
  unsigned short* W1bT = (unsigned short*)alloc((size_t)P1K * P1K * 2);
  unsigned short* W2Tb = (unsigned short*)alloc((size_t)P2K * P2K * 2);
  unsigned short* SAbT = (unsigned short*)alloc((size_t)524288 * 2);
  unsigned short* t2T  = (unsigned short*)alloc((size_t)512 * 512 * 2);
  unsigned short* t3T  = (unsigned short*)alloc((size_t)256 * 512 * 2);
  unsigned short* t4T  = (unsigned short*)alloc((size_t)128 * 256 * 2);
  (void)ws_size; (void)n_in; (void)out_size;

  int* co = cnt4;
  int* ci = cnt4 + N0;
  int* fo = cnt4 + 2 * N0;
  int* fi = cnt4 + 3 * N0;

  // --- graph build ---
  hipMemsetAsync(cnt4, 0, (size_t)4 * N0 * 4, stream);
  hipMemsetAsync(degsum2, 0, (size_t)P2K * 4, stream);
  hipMemsetAsync(W2f, 0, (size_t)P2K * P2K * 4, stream);
  count_edges<<<E / 256, 256, 0, stream>>>(src, dst, co, ci, E);
  exscan4096<<<1, 1024, 0, stream>>>(co, optr);
  exscan4096<<<1, 1024, 0, stream>>>(ci, iptr);
  fill_edges<<<E / 256, 256, 0, stream>>>(src, dst, optr, iptr, fo, fi, odst, isrc, E);
  dinv0_kernel<<<N0 / 256, 256, 0, stream>>>(optr, dinv0);
  diag2_kernel<<<N0, 64, 0, stream>>>(optr, odst, diag2);
  conv_T_bf16<<<512 * 512 / 256, 256, 0, stream>>>(theta2, t2T, 512, 512);
  conv_T_bf16<<<512 * 256 / 256, 256, 0, stream>>>(theta3, t3T, 512, 256);
  conv_T_bf16<<<256 * 128 / 256, 256, 0, stream>>>(theta4, t4T, 256, 128);

  // --- gcn0 (fp32): x[4096,128] -> x0[4096,256] ---
  mm32<<<(4096 / 32) * (256 / 64), 256, 0, stream>>>(x, theta0, SA, dinv0, nullptr, nullptr,
                                                     4096, 256, 128);
  gcn_spmm4<256><<<1024, 256, 0, stream>>>(iptr, isrc, SA, dinv0, b0, x0);

  // --- pool 1 ---
  score_kernel<<<4096, 256, 0, stream>>>(x0, 256, p1, score);
  topk_select<<<1, 1024, 0, stream>>>(score, 4096, 2048, perm1, vals1, rank1);
  build_W1<<<2048, 256, 0, stream>>>(optr, odst, perm1, rank1, W1b, dinv1);
  transpose_bf16<<<(2048 / 64) * (2048 / 64), 256, 0, stream>>>(W1b, W1bT, 2048);

  // --- gcn1 (fp32 sparse 2-hop, fused gather): x0[perm1]*vals1 -> x1b[2048,512] ---
  mm32<<<(2048 / 32) * (512 / 64), 256, 0, stream>>>(x0, theta1, SA, dinv1, perm1, vals1,
                                                     2048, 512, 256);
  atspmm_g<512><<<2048, 256, 0, stream>>>(iptr, isrc, rank1, SA, ZU);
  atspmm_epi<512><<<1024, 256, 0, stream>>>(iptr, isrc, perm1, diag2, ZU, SA, dinv1, b1, x1b);

  // --- pool 2 ---
  score_kernel<<<2048, 256, 0, stream>>>(x1b, 512, p2, score);
  topk_select<<<1, 1024, 0, stream>>>(score, 2048, 1024, perm2, vals2, rank2);
  mm_w2_mfma<<<256 * SPLITS, 256, 0, stream>>>(W1b, W1bT, perm2, W2f);
  w2_post<<<256, 256, 0, stream>>>(W2f, W2Tb, degsum2);
  dinv2_kernel<<<P2K / 256, 256, 0, stream>>>(degsum2, dinv2);

  // --- gcn2 (bf16 MFMA split-K): -> xb[1024,512] ---
  gemm_sk<false><<<128 * SPLITS, 256, 0, stream>>>(x1b, t2T, perm2, vals2, Pf,
                                                   1024, 512, 512, 8, 128);
  epi_red0_t<<<128, 256, 0, stream>>>(Pf, dinv2, SA, SAbT, 1024, 512);
  gemm_sk<true><<<128 * SPLITS, 256, 0, stream>>>(W2Tb, SAbT, nullptr, nullptr, Pf,
                                                  1024, 512, 1024, 8, 128);
  epi_red1<<<1024 * 512 / 1024, 256, 0, stream>>>(Pf, SA, dinv2, b2, xb, 1024, 512);
  mean_cols<<<512, 256, 0, stream>>>(xb, 1024, 512, out + 524288);

  // --- up block 1 (bf16 MFMA split-K, dense W1^T): -> xu[2048,256] ---
  add_up<<<2048 * 512 / 256, 256, 0, stream>>>(x1b, rank2, xb, x1b, 512, 2048 * 512);
  gemm_sk<false><<<128 * SPLITS, 256, 0, stream>>>(x1b, t3T, nullptr, nullptr, Pf,
                                                   2048, 256, 512, 4, 128);
  epi_red0_t<<<128, 256, 0, stream>>>(Pf, dinv1, SA, SAbT, 2048, 256);
  gemm_sk<true><<<128 * SPLITS, 256, 0, stream>>>(W1bT, SAbT, nullptr, nullptr, Pf,
                                                  2048, 256, 2048, 4, 128);
  epi_red1<<<2048 * 256 / 1024, 256, 0, stream>>>(Pf, SA, dinv1, b3, xu, 2048, 256);

  // --- up block 0 (bf16 mm split-K + fp32 sparse agg): -> out[4096,128] ---
  add_up<<<4096 * 256 / 256, 256, 0, stream>>>(x0, rank1, xu, x0, 256, 4096 * 256);
  gemm_sk<false><<<128 * SPLITS, 256, 0, stream>>>(x0, t4T, nullptr, nullptr, Pf,
                                                   4096, 128, 256, 2, 128);
  epi_red0_t<<<128, 256, 0, stream>>>(Pf, dinv0, SA, nullptr, 4096, 128);
  gcn_spmm4<128><<<512, 256, 0, stream>>>(iptr, isrc, SA, dinv0, b4, out);
}